// Round 1
// baseline (3902.175 us; speedup 1.0000x reference)
//
#include <hip/hip_runtime.h>

typedef unsigned short u16;
typedef unsigned int u32;
typedef __bf16 bf16x8 __attribute__((ext_vector_type(8)));
typedef float f32x4 __attribute__((ext_vector_type(4)));

#define LN_EPS 1e-5f

__device__ __forceinline__ u16 f2bf(float f) {
    u32 u = __float_as_uint(f);
    u += 0x7fffu + ((u >> 16) & 1u);
    return (u16)(u >> 16);
}

// ---------------- transpose f32 -> bf16 (out[c][r] = in[r][c]) ----------------
__global__ __launch_bounds__(256) void k_transpose_bf16(
    const float* __restrict__ in, u16* __restrict__ out, int R, int C)
{
    __shared__ float tile[32][33];
    int c0 = blockIdx.x * 32, r0 = blockIdx.y * 32;
    int tx = threadIdx.x & 31, ty = threadIdx.x >> 5;
#pragma unroll
    for (int i = 0; i < 4; i++)
        tile[ty + 8 * i][tx] = in[(long)(r0 + ty + 8 * i) * C + c0 + tx];
    __syncthreads();
#pragma unroll
    for (int i = 0; i < 4; i++)
        out[(long)(c0 + ty + 8 * i) * R + r0 + tx] = f2bf(tile[tx][ty + 8 * i]);
}

// ---------------- embedding: x = emb[id]*32 + pe ----------------
__global__ __launch_bounds__(256) void k_embed(
    const int* __restrict__ ids, const float* __restrict__ emb,
    const float* __restrict__ pe, float* __restrict__ xf, u16* __restrict__ xb)
{
    int row = blockIdx.x;          // b*512 + l
    int l = row & 511;
    long id = (long)ids[row];
    const float* e = emb + id * 1024;
    const float* p = pe + (long)l * 1024;
    float* xo = xf + (long)row * 1024;
    u16* xbo = xb + (long)row * 1024;
#pragma unroll
    for (int i = 0; i < 4; i++) {
        int idx = threadIdx.x + 256 * i;
        float v = e[idx] * 32.0f + p[idx];
        xo[idx] = v;
        xbo[idx] = f2bf(v);
    }
}

// ---------------- bf16 MFMA GEMM, NT form: C[m][n] = alpha * sum_k A[m][k]*B[n][k] + bias ----
// A: [M,K] bf16 row-major (lda), B: [N,K] bf16 row-major (ldb). Batched via blockIdx.z.
// biasMode: 0=none, 1=bias[n], 2=bias[m]
template <bool OUT_BF16>
__global__ __launch_bounds__(256) void k_gemm_nt(
    const u16* __restrict__ A, long lda, long sA,
    const u16* __restrict__ B, long ldb, long sB,
    void* __restrict__ Cm, long ldc, long sC,
    int M, int N, int K,
    const float* __restrict__ bias, int biasMode, float alpha)
{
    __shared__ u16 As[128][40];   // +8 pad -> 80B row stride, 2-way bank alias (free)
    __shared__ u16 Bs[128][40];
    int bz = blockIdx.z;
    A += (long)bz * sA;
    B += (long)bz * sB;
    int m0 = blockIdx.y * 128, n0 = blockIdx.x * 128;
    int tid = threadIdx.x;
    int lane = tid & 63, wid = tid >> 6;
    int wr = wid >> 1, wc = wid & 1;
    int quad = lane >> 4, l16 = lane & 15;

    f32x4 acc[4][4];
#pragma unroll
    for (int i = 0; i < 4; i++)
#pragma unroll
        for (int j = 0; j < 4; j++) acc[i][j] = {0.f, 0.f, 0.f, 0.f};

    int rowT = tid >> 2, segT = tid & 3;  // 8-elem chunk per thread; +64 rows on i=1
    for (int kb = 0; kb < K; kb += 32) {
#pragma unroll
        for (int i = 0; i < 2; i++) {
            int row = rowT + i * 64;
            int gm = m0 + row;
            uint4 v = make_uint4(0, 0, 0, 0);
            if (gm < M) v = *(const uint4*)(A + (long)gm * lda + kb + segT * 8);
            *(uint4*)&As[row][segT * 8] = v;
            int gn = n0 + row;
            uint4 w = make_uint4(0, 0, 0, 0);
            if (gn < N) w = *(const uint4*)(B + (long)gn * ldb + kb + segT * 8);
            *(uint4*)&Bs[row][segT * 8] = w;
        }
        __syncthreads();
        bf16x8 af[4], bg[4];
#pragma unroll
        for (int t = 0; t < 4; t++)
            af[t] = *(const bf16x8*)&As[wr * 64 + t * 16 + l16][quad * 8];
#pragma unroll
        for (int t = 0; t < 4; t++)
            bg[t] = *(const bf16x8*)&Bs[wc * 64 + t * 16 + l16][quad * 8];
#pragma unroll
        for (int i = 0; i < 4; i++)
#pragma unroll
            for (int j = 0; j < 4; j++)
                acc[i][j] = __builtin_amdgcn_mfma_f32_16x16x32_bf16(af[i], bg[j], acc[i][j], 0, 0, 0);
        __syncthreads();
    }

    // epilogue: C/D layout col=lane&15, row=quad*4+r (verified m89/m91)
#pragma unroll
    for (int i = 0; i < 4; i++) {
        int gm0 = m0 + wr * 64 + i * 16 + quad * 4;
#pragma unroll
        for (int j = 0; j < 4; j++) {
            int gn = n0 + wc * 64 + j * 16 + l16;
            if (gn >= N) continue;
            float bn = (biasMode == 1) ? bias[gn] : 0.0f;
#pragma unroll
            for (int r = 0; r < 4; r++) {
                int gm = gm0 + r;
                if (gm >= M) continue;
                float v = acc[i][j][r] * alpha + bn;
                if (biasMode == 2) v += bias[gm];
                long idx = (long)bz * sC + (long)gm * ldc + gn;
                if (OUT_BF16) ((u16*)Cm)[idx] = f2bf(v);
                else ((float*)Cm)[idx] = v;
            }
        }
    }
}

// ---------------- row softmax: fp32 in [rows,512] -> bf16 out ----------------
__global__ __launch_bounds__(256) void k_softmax(
    const float* __restrict__ S, u16* __restrict__ P)
{
    long row = blockIdx.x;
    const float* s = S + row * 512;
    u16* p = P + row * 512;
    int tid = threadIdx.x;
    float a = s[tid], b = s[tid + 256];
    float m = fmaxf(a, b);
    for (int off = 32; off; off >>= 1) m = fmaxf(m, __shfl_down(m, off));
    __shared__ float redm[4];
    if ((tid & 63) == 0) redm[tid >> 6] = m;
    __syncthreads();
    m = fmaxf(fmaxf(redm[0], redm[1]), fmaxf(redm[2], redm[3]));
    float ea = __expf(a - m), eb = __expf(b - m);
    float sum = ea + eb;
    for (int off = 32; off; off >>= 1) sum += __shfl_down(sum, off);
    __shared__ float reds[4];
    if ((tid & 63) == 0) reds[tid >> 6] = sum;
    __syncthreads();
    float inv = 1.0f / (reds[0] + reds[1] + reds[2] + reds[3]);
    p[tid] = f2bf(ea * inv);
    p[tid + 256] = f2bf(eb * inv);
}

// ---------------- x = LN(x + s) * g + beta ; also emit bf16 copy ----------------
__global__ __launch_bounds__(256) void k_add_ln(
    float* __restrict__ xf, u16* __restrict__ xb,
    const float* __restrict__ s, int sBroadcast,
    const float* __restrict__ g, const float* __restrict__ beta)
{
    int row = blockIdx.x;             // b*512 + l
    int srow = sBroadcast ? (row & 511) : row;
    float* x = xf + (long)row * 1024;
    u16* xo = xb + (long)row * 1024;
    const float* sp = s + (long)srow * 1024;
    int tid = threadIdx.x;
    float v[4];
    float sum = 0.f, sq = 0.f;
#pragma unroll
    for (int i = 0; i < 4; i++) {
        int idx = tid + i * 256;
        v[i] = x[idx] + sp[idx];
        sum += v[i];
        sq += v[i] * v[i];
    }
    for (int off = 32; off; off >>= 1) {
        sum += __shfl_down(sum, off);
        sq += __shfl_down(sq, off);
    }
    __shared__ float rs[4], rq[4];
    if ((tid & 63) == 0) { rs[tid >> 6] = sum; rq[tid >> 6] = sq; }
    __syncthreads();
    sum = rs[0] + rs[1] + rs[2] + rs[3];
    sq  = rq[0] + rq[1] + rq[2] + rq[3];
    float mean = sum * (1.f / 1024.f);
    float var = sq * (1.f / 1024.f) - mean * mean;
    float rstd = rsqrtf(var + LN_EPS);
#pragma unroll
    for (int i = 0; i < 4; i++) {
        int idx = tid + i * 256;
        float y = (v[i] - mean) * rstd * g[idx] + beta[idx];
        x[idx] = y;
        xo[idx] = f2bf(y);
    }
}

// ---------------- pooled[b][d] = mean_l x[b][l][d] ----------------
__global__ __launch_bounds__(256) void k_pool(
    const float* __restrict__ xf, float* __restrict__ pooled)
{
    int b = blockIdx.x, dchunk = blockIdx.y;
    int t = threadIdx.x & 63, lpart = threadIdx.x >> 6;
    int d = dchunk * 64 + t;
    const float* x = xf + (long)b * 512 * 1024;
    float s = 0.f;
    for (int l = lpart; l < 512; l += 4) s += x[(long)l * 1024 + d];
    __shared__ float red[4][64];
    red[lpart][t] = s;
    __syncthreads();
    if (threadIdx.x < 64) {
        float tot = red[0][threadIdx.x] + red[1][threadIdx.x] + red[2][threadIdx.x] + red[3][threadIdx.x];
        pooled[b * 1024 + dchunk * 64 + threadIdx.x] = tot * (1.f / 512.f);
    }
}

// ---------------- out[b][c] = pooled[b] . wf[:,c] + bf[c] ----------------
__global__ __launch_bounds__(256) void k_head(
    const float* __restrict__ pooled, const float* __restrict__ wf,
    const float* __restrict__ bfin, float* __restrict__ out)
{
    int b = blockIdx.x / 10, c = blockIdx.x % 10;
    const float* p = pooled + b * 1024;
    float s = 0.f;
    for (int d = threadIdx.x; d < 1024; d += 256) s += p[d] * wf[(long)d * 10 + c];
    for (int off = 32; off; off >>= 1) s += __shfl_down(s, off);
    __shared__ float red[4];
    if ((threadIdx.x & 63) == 0) red[threadIdx.x >> 6] = s;
    __syncthreads();
    if (threadIdx.x == 0) out[b * 10 + c] = red[0] + red[1] + red[2] + red[3] + bfin[c];
}

// ---------------- host side ----------------
static void gemm(bool outBf16, const u16* A, long lda, long sA,
                 const u16* B, long ldb, long sB,
                 void* C, long ldc, long sC,
                 int M, int N, int K, const float* bias, int biasMode, float alpha,
                 int batch, hipStream_t st)
{
    dim3 g((N + 127) / 128, (M + 127) / 128, batch);
    if (outBf16)
        k_gemm_nt<true><<<g, 256, 0, st>>>(A, lda, sA, B, ldb, sB, C, ldc, sC, M, N, K, bias, biasMode, alpha);
    else
        k_gemm_nt<false><<<g, 256, 0, st>>>(A, lda, sA, B, ldb, sB, C, ldc, sC, M, N, K, bias, biasMode, alpha);
}

extern "C" void kernel_launch(void* const* d_in, const int* in_sizes, int n_in,
                              void* d_out, int out_size, void* d_ws, size_t ws_size,
                              hipStream_t stream)
{
    const int* ids   = (const int*)d_in[0];
    const float* emb = (const float*)d_in[1];
    const float* pe  = (const float*)d_in[2];
    const float* wq  = (const float*)d_in[3];
    const float* bq  = (const float*)d_in[4];
    const float* wk  = (const float*)d_in[5];
    const float* bk  = (const float*)d_in[6];
    const float* wv  = (const float*)d_in[7];
    const float* bv  = (const float*)d_in[8];
    const float* wo  = (const float*)d_in[9];
    const float* bo  = (const float*)d_in[10];
    const float* w1  = (const float*)d_in[11];
    const float* b1  = (const float*)d_in[12];
    const float* w2  = (const float*)d_in[13];
    const float* b2  = (const float*)d_in[14];
    const float* g1  = (const float*)d_in[15];
    const float* be1 = (const float*)d_in[16];
    const float* g2  = (const float*)d_in[17];
    const float* be2 = (const float*)d_in[18];
    const float* wf  = (const float*)d_in[19];
    const float* bfi = (const float*)d_in[20];
    float* out = (float*)d_out;

    char* base = (char*)d_ws;
    size_t off = 0;
    auto alloc = [&](size_t bytes) {
        char* p = base + off;
        off = (off + bytes + 255) & ~(size_t)255;
        return p;
    };
    float* xf   = (float*)alloc(16UL * 512 * 1024 * 4);   // fp32 residual stream [B,L,D]
    u16*   xb   = (u16*)  alloc(16UL * 512 * 1024 * 2);   // bf16 copy of x
    u16*   wqT  = (u16*)  alloc(1024UL * 1024 * 2);
    u16*   wkT  = (u16*)  alloc(1024UL * 1024 * 2);
    u16*   wvT  = (u16*)  alloc(1024UL * 1024 * 2);
    u16*   woT  = (u16*)  alloc(1024UL * 1024 * 2);
    u16*   w1T  = (u16*)  alloc(4096UL * 1024 * 2);       // [F,D]
    u16*   w2T  = (u16*)  alloc(1024UL * 4096 * 2);       // [D,F]
    u16*   qb   = (u16*)  alloc(512UL * 1024 * 2);
    u16*   kbuf = (u16*)  alloc(512UL * 1024 * 2);
    u16*   vT   = (u16*)  alloc(1024UL * 512 * 2);        // v transposed [D,L]
    float* sc   = (float*)alloc(16UL * 512 * 512 * 4);    // scores [H,L,L]
    u16*   P    = (u16*)  alloc(16UL * 512 * 512 * 2);    // softmax probs bf16
    u16*   Ob   = (u16*)  alloc(512UL * 1024 * 2);        // attn context bf16 [L,D]
    float* src2 = (float*)alloc(512UL * 1024 * 4);
    u16*   Hb   = (u16*)  alloc(8192UL * 4096 * 2);       // FFN hidden bf16
    float* ffb  = (float*)alloc(8192UL * 1024 * 4);
    float* pooled = (float*)alloc(16UL * 1024 * 4);

    // weight conversion (every launch: ws re-poisoned)
    k_transpose_bf16<<<dim3(32, 32), 256, 0, stream>>>(wq, wqT, 1024, 1024);
    k_transpose_bf16<<<dim3(32, 32), 256, 0, stream>>>(wk, wkT, 1024, 1024);
    k_transpose_bf16<<<dim3(32, 32), 256, 0, stream>>>(wv, wvT, 1024, 1024);
    k_transpose_bf16<<<dim3(32, 32), 256, 0, stream>>>(wo, woT, 1024, 1024);
    k_transpose_bf16<<<dim3(128, 32), 256, 0, stream>>>(w1, w1T, 1024, 4096);
    k_transpose_bf16<<<dim3(32, 128), 256, 0, stream>>>(w2, w2T, 4096, 1024);

    k_embed<<<8192, 256, 0, stream>>>(ids, emb, pe, xf, xb);

    for (int layer = 0; layer < 6; layer++) {
        // q,k for batch 0 only (rows 0..511 of xb): [512,1024]
        gemm(true, xb, 1024, 0, wqT, 1024, 0, qb,   1024, 0, 512, 1024, 1024, bq, 1, 1.f, 1, stream);
        gemm(true, xb, 1024, 0, wkT, 1024, 0, kbuf, 1024, 0, 512, 1024, 1024, bk, 1, 1.f, 1, stream);
        // vT[d][l]: swap operands -> output transposed; bias per-row (d)
        gemm(true, wvT, 1024, 0, xb, 1024, 0, vT, 512, 0, 1024, 512, 1024, bv, 2, 1.f, 1, stream);
        // scores[h] = Q_h . K_h^T * 0.125  (batched over heads; per-head col offset h*64)
        gemm(false, qb, 1024, 64, kbuf, 1024, 64, sc, 512, 512L * 512, 512, 512, 64, nullptr, 0, 0.125f, 16, stream);
        k_softmax<<<16 * 512, 256, 0, stream>>>(sc, P);
        // O_h = P_h . V_h  (B operand = vT rows h*64..h*64+63)
        gemm(true, P, 512, 512L * 512, vT, 512, 64L * 512, Ob, 1024, 64, 512, 64, 512, nullptr, 0, 1.f, 16, stream);
        // src2 = O . wo + bo
        gemm(false, Ob, 1024, 0, woT, 1024, 0, src2, 1024, 0, 512, 1024, 1024, bo, 1, 1.f, 1, stream);
        k_add_ln<<<8192, 256, 0, stream>>>(xf, xb, src2, 1, g1, be1);
        // FFN
        gemm(true, xb, 1024, 0, w1T, 1024, 0, Hb, 4096, 0, 8192, 4096, 1024, b1, 1, 1.f, 1, stream);
        gemm(false, Hb, 4096, 0, w2T, 4096, 0, ffb, 1024, 0, 8192, 1024, 4096, b2, 1, 1.f, 1, stream);
        k_add_ln<<<8192, 256, 0, stream>>>(xf, xb, ffb, 0, g2, be2);
    }

    k_pool<<<dim3(16, 16), 256, 0, stream>>>(xf, pooled);
    k_head<<<160, 256, 0, stream>>>(pooled, wf, bfi, out);
}

// Round 2
// 2967.951 us; speedup vs baseline: 1.3148x; 1.3148x over previous
//
#include <hip/hip_runtime.h>

typedef unsigned short u16;
typedef unsigned int u32;
typedef __bf16 bf16x8 __attribute__((ext_vector_type(8)));
typedef float f32x4 __attribute__((ext_vector_type(4)));

#define LN_EPS 1e-5f

__device__ __forceinline__ u16 f2bf(float f) {
    u32 u = __float_as_uint(f);
    u += 0x7fffu + ((u >> 16) & 1u);
    return (u16)(u >> 16);
}

// async global->LDS, 16B per lane; lds base must be wave-uniform (HW: base + lane*16)
#define ASYNC_CP16(g, l)                                                      \
    __builtin_amdgcn_global_load_lds(                                         \
        (const __attribute__((address_space(1))) u32*)(g),                    \
        (__attribute__((address_space(3))) u32*)(l), 16, 0, 0)

// ---------------- transpose f32 -> bf16 (out[c][r] = in[r][c]) ----------------
__global__ __launch_bounds__(256) void k_transpose_bf16(
    const float* __restrict__ in, u16* __restrict__ out, int R, int C)
{
    __shared__ float tile[32][33];
    int c0 = blockIdx.x * 32, r0 = blockIdx.y * 32;
    int tx = threadIdx.x & 31, ty = threadIdx.x >> 5;
#pragma unroll
    for (int i = 0; i < 4; i++)
        tile[ty + 8 * i][tx] = in[(long)(r0 + ty + 8 * i) * C + c0 + tx];
    __syncthreads();
#pragma unroll
    for (int i = 0; i < 4; i++)
        out[(long)(c0 + ty + 8 * i) * R + r0 + tx] = f2bf(tile[tx][ty + 8 * i]);
}

// ---------------- embedding: x = emb[id]*32 + pe ----------------
__global__ __launch_bounds__(256) void k_embed(
    const int* __restrict__ ids, const float* __restrict__ emb,
    const float* __restrict__ pe, float* __restrict__ xf, u16* __restrict__ xb)
{
    int row = blockIdx.x;          // b*512 + l
    int l = row & 511;
    long id = (long)ids[row];
    const float* e = emb + id * 1024;
    const float* p = pe + (long)l * 1024;
    float* xo = xf + (long)row * 1024;
    u16* xbo = xb + (long)row * 1024;
#pragma unroll
    for (int i = 0; i < 4; i++) {
        int idx = threadIdx.x + 256 * i;
        float v = e[idx] * 32.0f + p[idx];
        xo[idx] = v;
        xbo[idx] = f2bf(v);
    }
}

// ---------------- bf16 MFMA GEMM, NT form: C[m][n] = alpha * sum_k A[m][k]*B[n][k] + bias ----
// A: [M,K] bf16 row-major (lda), B: [N,K] bf16 row-major (ldb). Batched via blockIdx.z.
// biasMode: 0=none, 1=bias[n], 2=bias[m].
// m97 structure: unpadded LDS [128][32], global_load_lds width=16 staging.
template <bool OUT_BF16>
__global__ __launch_bounds__(256) void k_gemm_nt(
    const u16* __restrict__ A, long lda, long sA,
    const u16* __restrict__ B, long ldb, long sB,
    void* __restrict__ Cm, long ldc, long sC,
    int M, int N, int K,
    const float* __restrict__ bias, int biasMode, float alpha)
{
    __shared__ u16 As[128 * 32];   // unpadded: global_load_lds lands lane*16B contiguous
    __shared__ u16 Bs[128 * 32];
    int bz = blockIdx.z;
    A += (long)bz * sA;
    B += (long)bz * sB;
    int m0 = blockIdx.y * 128, n0 = blockIdx.x * 128;
    int tid = threadIdx.x;
    int lane = tid & 63, wid = tid >> 6;
    int wr = wid >> 1, wc = wid & 1;
    int quad = lane >> 4, l16 = lane & 15;

    f32x4 acc[4][4];
#pragma unroll
    for (int i = 0; i < 4; i++)
#pragma unroll
        for (int j = 0; j < 4; j++) acc[i][j] = {0.f, 0.f, 0.f, 0.f};

    // staging: wave w covers LDS rows [w*32, w*32+32): two 1KB chunks (16 rows each).
    // lane l -> row (chunk*16 + l/4), 8-elem segment (l%4)*8 ; LDS offset = lane*16B from chunk base.
    int rloc0 = (wid * 2 + 0) * 16 + (lane >> 2);
    int rloc1 = (wid * 2 + 1) * 16 + (lane >> 2);
    int seg = (lane & 3) * 8;
    u16* AsB0 = &As[(wid * 2 + 0) * 512];
    u16* AsB1 = &As[(wid * 2 + 1) * 512];
    u16* BsB0 = &Bs[(wid * 2 + 0) * 512];
    u16* BsB1 = &Bs[(wid * 2 + 1) * 512];
    // clamp global rows (tails: PV GEMM has N=64); epilogue guards the output
    int gmA0 = min(m0 + rloc0, M - 1), gmA1 = min(m0 + rloc1, M - 1);
    int gnB0 = min(n0 + rloc0, N - 1), gnB1 = min(n0 + rloc1, N - 1);
    const u16* pA0 = A + (long)gmA0 * lda + seg;
    const u16* pA1 = A + (long)gmA1 * lda + seg;
    const u16* pB0 = B + (long)gnB0 * ldb + seg;
    const u16* pB1 = B + (long)gnB1 * ldb + seg;

    for (int kb = 0; kb < K; kb += 32) {
        ASYNC_CP16(pA0 + kb, AsB0);
        ASYNC_CP16(pA1 + kb, AsB1);
        ASYNC_CP16(pB0 + kb, BsB0);
        ASYNC_CP16(pB1 + kb, BsB1);
        __syncthreads();   // emits s_waitcnt vmcnt(0) before s_barrier -> staging visible
        bf16x8 af[4], bg[4];
#pragma unroll
        for (int t = 0; t < 4; t++)
            af[t] = *(const bf16x8*)&As[(wr * 64 + t * 16 + l16) * 32 + quad * 8];
#pragma unroll
        for (int t = 0; t < 4; t++)
            bg[t] = *(const bf16x8*)&Bs[(wc * 64 + t * 16 + l16) * 32 + quad * 8];
#pragma unroll
        for (int i = 0; i < 4; i++)
#pragma unroll
            for (int j = 0; j < 4; j++)
                acc[i][j] = __builtin_amdgcn_mfma_f32_16x16x32_bf16(af[i], bg[j], acc[i][j], 0, 0, 0);
        __syncthreads();
    }

    // epilogue: C/D layout col=lane&15, row=quad*4+r (verified m89/m91)
#pragma unroll
    for (int i = 0; i < 4; i++) {
        int gm0 = m0 + wr * 64 + i * 16 + quad * 4;
#pragma unroll
        for (int j = 0; j < 4; j++) {
            int gn = n0 + wc * 64 + j * 16 + l16;
            if (gn >= N) continue;
            float bn = (biasMode == 1) ? bias[gn] : 0.0f;
#pragma unroll
            for (int r = 0; r < 4; r++) {
                int gm = gm0 + r;
                if (gm >= M) continue;
                float v = acc[i][j][r] * alpha + bn;
                if (biasMode == 2) v += bias[gm];
                long idx = (long)bz * sC + (long)gm * ldc + gn;
                if (OUT_BF16) ((u16*)Cm)[idx] = f2bf(v);
                else ((float*)Cm)[idx] = v;
            }
        }
    }
}

// ---------------- row softmax: fp32 in [rows,512] -> bf16 out ----------------
__global__ __launch_bounds__(256) void k_softmax(
    const float* __restrict__ S, u16* __restrict__ P)
{
    long row = blockIdx.x;
    const float* s = S + row * 512;
    u16* p = P + row * 512;
    int tid = threadIdx.x;
    float a = s[tid], b = s[tid + 256];
    float m = fmaxf(a, b);
    for (int off = 32; off; off >>= 1) m = fmaxf(m, __shfl_down(m, off));
    __shared__ float redm[4];
    if ((tid & 63) == 0) redm[tid >> 6] = m;
    __syncthreads();
    m = fmaxf(fmaxf(redm[0], redm[1]), fmaxf(redm[2], redm[3]));
    float ea = __expf(a - m), eb = __expf(b - m);
    float sum = ea + eb;
    for (int off = 32; off; off >>= 1) sum += __shfl_down(sum, off);
    __shared__ float reds[4];
    if ((tid & 63) == 0) reds[tid >> 6] = sum;
    __syncthreads();
    float inv = 1.0f / (reds[0] + reds[1] + reds[2] + reds[3]);
    p[tid] = f2bf(ea * inv);
    p[tid + 256] = f2bf(eb * inv);
}

// ---------------- x = LN(x + s) * g + beta ; also emit bf16 copy ----------------
__global__ __launch_bounds__(256) void k_add_ln(
    float* __restrict__ xf, u16* __restrict__ xb,
    const float* __restrict__ s, int sBroadcast,
    const float* __restrict__ g, const float* __restrict__ beta)
{
    int row = blockIdx.x;             // b*512 + l
    int srow = sBroadcast ? (row & 511) : row;
    float* x = xf + (long)row * 1024;
    u16* xo = xb + (long)row * 1024;
    const float* sp = s + (long)srow * 1024;
    int tid = threadIdx.x;
    float v[4];
    float sum = 0.f, sq = 0.f;
#pragma unroll
    for (int i = 0; i < 4; i++) {
        int idx = tid + i * 256;
        v[i] = x[idx] + sp[idx];
        sum += v[i];
        sq += v[i] * v[i];
    }
    for (int off = 32; off; off >>= 1) {
        sum += __shfl_down(sum, off);
        sq += __shfl_down(sq, off);
    }
    __shared__ float rs[4], rq[4];
    if ((tid & 63) == 0) { rs[tid >> 6] = sum; rq[tid >> 6] = sq; }
    __syncthreads();
    sum = rs[0] + rs[1] + rs[2] + rs[3];
    sq  = rq[0] + rq[1] + rq[2] + rq[3];
    float mean = sum * (1.f / 1024.f);
    float var = sq * (1.f / 1024.f) - mean * mean;
    float rstd = rsqrtf(var + LN_EPS);
#pragma unroll
    for (int i = 0; i < 4; i++) {
        int idx = tid + i * 256;
        float y = (v[i] - mean) * rstd * g[idx] + beta[idx];
        x[idx] = y;
        xo[idx] = f2bf(y);
    }
}

// ---------------- pooled[b][d] = mean_l x[b][l][d] ----------------
__global__ __launch_bounds__(256) void k_pool(
    const float* __restrict__ xf, float* __restrict__ pooled)
{
    int b = blockIdx.x, dchunk = blockIdx.y;
    int t = threadIdx.x & 63, lpart = threadIdx.x >> 6;
    int d = dchunk * 64 + t;
    const float* x = xf + (long)b * 512 * 1024;
    float s = 0.f;
    for (int l = lpart; l < 512; l += 4) s += x[(long)l * 1024 + d];
    __shared__ float red[4][64];
    red[lpart][t] = s;
    __syncthreads();
    if (threadIdx.x < 64) {
        float tot = red[0][threadIdx.x] + red[1][threadIdx.x] + red[2][threadIdx.x] + red[3][threadIdx.x];
        pooled[b * 1024 + dchunk * 64 + threadIdx.x] = tot * (1.f / 512.f);
    }
}

// ---------------- out[b][c] = pooled[b] . wf[:,c] + bf[c] ----------------
__global__ __launch_bounds__(256) void k_head(
    const float* __restrict__ pooled, const float* __restrict__ wf,
    const float* __restrict__ bfin, float* __restrict__ out)
{
    int b = blockIdx.x / 10, c = blockIdx.x % 10;
    const float* p = pooled + b * 1024;
    float s = 0.f;
    for (int d = threadIdx.x; d < 1024; d += 256) s += p[d] * wf[(long)d * 10 + c];
    for (int off = 32; off; off >>= 1) s += __shfl_down(s, off);
    __shared__ float red[4];
    if ((threadIdx.x & 63) == 0) red[threadIdx.x >> 6] = s;
    __syncthreads();
    if (threadIdx.x == 0) out[b * 10 + c] = red[0] + red[1] + red[2] + red[3] + bfin[c];
}

// ---------------- host side ----------------
static void gemm(bool outBf16, const u16* A, long lda, long sA,
                 const u16* B, long ldb, long sB,
                 void* C, long ldc, long sC,
                 int M, int N, int K, const float* bias, int biasMode, float alpha,
                 int batch, hipStream_t st)
{
    dim3 g((N + 127) / 128, (M + 127) / 128, batch);
    if (outBf16)
        k_gemm_nt<true><<<g, 256, 0, st>>>(A, lda, sA, B, ldb, sB, C, ldc, sC, M, N, K, bias, biasMode, alpha);
    else
        k_gemm_nt<false><<<g, 256, 0, st>>>(A, lda, sA, B, ldb, sB, C, ldc, sC, M, N, K, bias, biasMode, alpha);
}

extern "C" void kernel_launch(void* const* d_in, const int* in_sizes, int n_in,
                              void* d_out, int out_size, void* d_ws, size_t ws_size,
                              hipStream_t stream)
{
    const int* ids   = (const int*)d_in[0];
    const float* emb = (const float*)d_in[1];
    const float* pe  = (const float*)d_in[2];
    const float* wq  = (const float*)d_in[3];
    const float* bq  = (const float*)d_in[4];
    const float* wk  = (const float*)d_in[5];
    const float* bk  = (const float*)d_in[6];
    const float* wv  = (const float*)d_in[7];
    const float* bv  = (const float*)d_in[8];
    const float* wo  = (const float*)d_in[9];
    const float* bo  = (const float*)d_in[10];
    const float* w1  = (const float*)d_in[11];
    const float* b1  = (const float*)d_in[12];
    const float* w2  = (const float*)d_in[13];
    const float* b2  = (const float*)d_in[14];
    const float* g1  = (const float*)d_in[15];
    const float* be1 = (const float*)d_in[16];
    const float* g2  = (const float*)d_in[17];
    const float* be2 = (const float*)d_in[18];
    const float* wf  = (const float*)d_in[19];
    const float* bfi = (const float*)d_in[20];
    float* out = (float*)d_out;

    char* base = (char*)d_ws;
    size_t off = 0;
    auto alloc = [&](size_t bytes) {
        char* p = base + off;
        off = (off + bytes + 255) & ~(size_t)255;
        return p;
    };
    float* xf   = (float*)alloc(16UL * 512 * 1024 * 4);   // fp32 residual stream [B,L,D]
    u16*   xb   = (u16*)  alloc(16UL * 512 * 1024 * 2);   // bf16 copy of x
    u16*   wqT  = (u16*)  alloc(1024UL * 1024 * 2);
    u16*   wkT  = (u16*)  alloc(1024UL * 1024 * 2);
    u16*   wvT  = (u16*)  alloc(1024UL * 1024 * 2);
    u16*   woT  = (u16*)  alloc(1024UL * 1024 * 2);
    u16*   w1T  = (u16*)  alloc(4096UL * 1024 * 2);       // [F,D]
    u16*   w2T  = (u16*)  alloc(1024UL * 4096 * 2);       // [D,F]
    u16*   qb   = (u16*)  alloc(512UL * 1024 * 2);
    u16*   kbuf = (u16*)  alloc(512UL * 1024 * 2);
    u16*   vT   = (u16*)  alloc(1024UL * 512 * 2);        // v transposed [D,L]
    float* sc   = (float*)alloc(16UL * 512 * 512 * 4);    // scores [H,L,L]
    u16*   P    = (u16*)  alloc(16UL * 512 * 512 * 2);    // softmax probs bf16
    u16*   Ob   = (u16*)  alloc(512UL * 1024 * 2);        // attn context bf16 [L,D]
    float* src2 = (float*)alloc(512UL * 1024 * 4);
    u16*   Hb   = (u16*)  alloc(8192UL * 4096 * 2);       // FFN hidden bf16
    float* ffb  = (float*)alloc(8192UL * 1024 * 4);
    float* pooled = (float*)alloc(16UL * 1024 * 4);

    // weight conversion (every launch: ws re-poisoned)
    k_transpose_bf16<<<dim3(32, 32), 256, 0, stream>>>(wq, wqT, 1024, 1024);
    k_transpose_bf16<<<dim3(32, 32), 256, 0, stream>>>(wk, wkT, 1024, 1024);
    k_transpose_bf16<<<dim3(32, 32), 256, 0, stream>>>(wv, wvT, 1024, 1024);
    k_transpose_bf16<<<dim3(32, 32), 256, 0, stream>>>(wo, woT, 1024, 1024);
    k_transpose_bf16<<<dim3(128, 32), 256, 0, stream>>>(w1, w1T, 1024, 4096);
    k_transpose_bf16<<<dim3(32, 128), 256, 0, stream>>>(w2, w2T, 4096, 1024);

    k_embed<<<8192, 256, 0, stream>>>(ids, emb, pe, xf, xb);

    for (int layer = 0; layer < 6; layer++) {
        // q,k for batch 0 only (rows 0..511 of xb): [512,1024]
        gemm(true, xb, 1024, 0, wqT, 1024, 0, qb,   1024, 0, 512, 1024, 1024, bq, 1, 1.f, 1, stream);
        gemm(true, xb, 1024, 0, wkT, 1024, 0, kbuf, 1024, 0, 512, 1024, 1024, bk, 1, 1.f, 1, stream);
        // vT[d][l]: swap operands -> output transposed; bias per-row (d)
        gemm(true, wvT, 1024, 0, xb, 1024, 0, vT, 512, 0, 1024, 512, 1024, bv, 2, 1.f, 1, stream);
        // scores[h] = Q_h . K_h^T * 0.125  (batched over heads; per-head col offset h*64)
        gemm(false, qb, 1024, 64, kbuf, 1024, 64, sc, 512, 512L * 512, 512, 512, 64, nullptr, 0, 0.125f, 16, stream);
        k_softmax<<<16 * 512, 256, 0, stream>>>(sc, P);
        // O_h = P_h . V_h  (B operand = vT rows h*64..h*64+63)
        gemm(true, P, 512, 512L * 512, vT, 512, 64L * 512, Ob, 1024, 64, 512, 64, 512, nullptr, 0, 1.f, 16, stream);
        // src2 = O . wo + bo
        gemm(false, Ob, 1024, 0, woT, 1024, 0, src2, 1024, 0, 512, 1024, 1024, bo, 1, 1.f, 1, stream);
        k_add_ln<<<8192, 256, 0, stream>>>(xf, xb, src2, 1, g1, be1);
        // FFN
        gemm(true, xb, 1024, 0, w1T, 1024, 0, Hb, 4096, 0, 8192, 4096, 1024, b1, 1, 1.f, 1, stream);
        gemm(false, Hb, 4096, 0, w2T, 4096, 0, ffb, 1024, 0, 8192, 1024, 4096, b2, 1, 1.f, 1, stream);
        k_add_ln<<<8192, 256, 0, stream>>>(xf, xb, ffb, 0, g2, be2);
    }

    k_pool<<<dim3(16, 16), 256, 0, stream>>>(xf, pooled);
    k_head<<<160, 256, 0, stream>>>(pooled, wf, bfi, out);
}

// Round 3
// 2299.636 us; speedup vs baseline: 1.6969x; 1.2906x over previous
//
#include <hip/hip_runtime.h>

typedef unsigned short u16;
typedef unsigned int u32;
typedef __bf16 bf16x8 __attribute__((ext_vector_type(8)));
typedef float f32x4 __attribute__((ext_vector_type(4)));

#define LN_EPS 1e-5f

__device__ __forceinline__ u16 f2bf(float f) {
    u32 u = __float_as_uint(f);
    u += 0x7fffu + ((u >> 16) & 1u);
    return (u16)(u >> 16);
}

// async global->LDS, 16B per lane; lds base must be wave-uniform (HW: base + lane*16)
#define ASYNC_CP16(g, l)                                                      \
    __builtin_amdgcn_global_load_lds(                                         \
        (const __attribute__((address_space(1))) u32*)(g),                    \
        (__attribute__((address_space(3))) u32*)(l), 16, 0, 0)

// ---------------- transpose f32 -> bf16 (out[c][r] = in[r][c]) ----------------
__global__ __launch_bounds__(256) void k_transpose_bf16(
    const float* __restrict__ in, u16* __restrict__ out, int R, int C, long ldo)
{
    __shared__ float tile[32][33];
    int c0 = blockIdx.x * 32, r0 = blockIdx.y * 32;
    int tx = threadIdx.x & 31, ty = threadIdx.x >> 5;
#pragma unroll
    for (int i = 0; i < 4; i++)
        tile[ty + 8 * i][tx] = in[(long)(r0 + ty + 8 * i) * C + c0 + tx];
    __syncthreads();
#pragma unroll
    for (int i = 0; i < 4; i++)
        out[(long)(c0 + ty + 8 * i) * ldo + r0 + tx] = f2bf(tile[tx][ty + 8 * i]);
}

// ---------------- transpose bf16 -> bf16 (out[c][r] = in[r][c]) ----------------
__global__ __launch_bounds__(256) void k_transpose_bb(
    const u16* __restrict__ in, long ldi, u16* __restrict__ out, long ldo)
{
    __shared__ u16 tile[32][33];
    int c0 = blockIdx.x * 32, r0 = blockIdx.y * 32;
    int tx = threadIdx.x & 31, ty = threadIdx.x >> 5;
#pragma unroll
    for (int i = 0; i < 4; i++)
        tile[ty + 8 * i][tx] = in[(long)(r0 + ty + 8 * i) * ldi + c0 + tx];
    __syncthreads();
#pragma unroll
    for (int i = 0; i < 4; i++)
        out[(long)(c0 + ty + 8 * i) * ldo + r0 + tx] = tile[tx][ty + 8 * i];
}

// ---------------- concat 3 bias vectors [1024] -> [3072] ----------------
__global__ __launch_bounds__(256) void k_concat3(
    const float* __restrict__ a, const float* __restrict__ b,
    const float* __restrict__ c, float* __restrict__ o)
{
    int i = blockIdx.x * 256 + threadIdx.x;
    float v = (i < 1024) ? a[i] : (i < 2048 ? b[i - 1024] : c[i - 2048]);
    o[i] = v;
}

// ---------------- embedding: x = emb[id]*32 + pe ----------------
__global__ __launch_bounds__(256) void k_embed(
    const int* __restrict__ ids, const float* __restrict__ emb,
    const float* __restrict__ pe, float* __restrict__ xf, u16* __restrict__ xb)
{
    int row = blockIdx.x;          // b*512 + l
    int l = row & 511;
    long id = (long)ids[row];
    const float* e = emb + id * 1024;
    const float* p = pe + (long)l * 1024;
    float* xo = xf + (long)row * 1024;
    u16* xbo = xb + (long)row * 1024;
#pragma unroll
    for (int i = 0; i < 4; i++) {
        int idx = threadIdx.x + 256 * i;
        float v = e[idx] * 32.0f + p[idx];
        xo[idx] = v;
        xbo[idx] = f2bf(v);
    }
}

// ---------------- bf16 MFMA GEMM, NT form: C[m][n] = alpha * sum_k A[m][k]*B[n][k] + bias ----
// A: [M,K] bf16 row-major (lda), B: [N,K] bf16 row-major (ldb). Batched via blockIdx.z.
// biasMode: 0=none, 1=bias[n], 2=bias[m].
// m97 structure + BK=64: two conflict-free [128][32] K-planes per operand,
// 8x global_load_lds width=16 per iter, 32 MFMA per barrier pair.
template <bool OUT_BF16>
__global__ __launch_bounds__(256) void k_gemm_nt(
    const u16* __restrict__ A, long lda, long sA,
    const u16* __restrict__ B, long ldb, long sB,
    void* __restrict__ Cm, long ldc, long sC,
    int M, int N, int K,
    const float* __restrict__ bias, int biasMode, float alpha)
{
    __shared__ u16 As[2 * 128 * 32];   // [kh][row][32], unpadded per plane
    __shared__ u16 Bs[2 * 128 * 32];
    int bz = blockIdx.z;
    A += (long)bz * sA;
    B += (long)bz * sB;
    int m0 = blockIdx.y * 128, n0 = blockIdx.x * 128;
    int tid = threadIdx.x;
    int lane = tid & 63, wid = tid >> 6;
    int wr = wid >> 1, wc = wid & 1;
    int quad = lane >> 4, l16 = lane & 15;

    f32x4 acc[4][4];
#pragma unroll
    for (int i = 0; i < 4; i++)
#pragma unroll
        for (int j = 0; j < 4; j++) acc[i][j] = {0.f, 0.f, 0.f, 0.f};

    // staging: per K-plane, wave w covers rows [w*32, w*32+32) as two 16-row chunks.
    // lane l -> row chunk*16 + l/4, k-seg (l%4)*8 ; LDS offset = lane*16B from chunk base.
    int rloc0 = (wid * 2 + 0) * 16 + (lane >> 2);
    int rloc1 = (wid * 2 + 1) * 16 + (lane >> 2);
    int seg = (lane & 3) * 8;
    u16* a00 = &As[(wid * 2 + 0) * 512];          // kh=0, half 0
    u16* a01 = &As[(wid * 2 + 1) * 512];          // kh=0, half 1
    u16* a10 = &As[4096 + (wid * 2 + 0) * 512];   // kh=1
    u16* a11 = &As[4096 + (wid * 2 + 1) * 512];
    u16* b00 = &Bs[(wid * 2 + 0) * 512];
    u16* b01 = &Bs[(wid * 2 + 1) * 512];
    u16* b10 = &Bs[4096 + (wid * 2 + 0) * 512];
    u16* b11 = &Bs[4096 + (wid * 2 + 1) * 512];
    // clamp global rows (tails: PV GEMM has N=64); epilogue guards the output
    int gmA0 = min(m0 + rloc0, M - 1), gmA1 = min(m0 + rloc1, M - 1);
    int gnB0 = min(n0 + rloc0, N - 1), gnB1 = min(n0 + rloc1, N - 1);
    const u16* pA0 = A + (long)gmA0 * lda + seg;
    const u16* pA1 = A + (long)gmA1 * lda + seg;
    const u16* pB0 = B + (long)gnB0 * ldb + seg;
    const u16* pB1 = B + (long)gnB1 * ldb + seg;

    for (int kb = 0; kb < K; kb += 64) {
        ASYNC_CP16(pA0 + kb,      a00);
        ASYNC_CP16(pA1 + kb,      a01);
        ASYNC_CP16(pA0 + kb + 32, a10);
        ASYNC_CP16(pA1 + kb + 32, a11);
        ASYNC_CP16(pB0 + kb,      b00);
        ASYNC_CP16(pB1 + kb,      b01);
        ASYNC_CP16(pB0 + kb + 32, b10);
        ASYNC_CP16(pB1 + kb + 32, b11);
        __syncthreads();   // vmcnt(0) drain + barrier -> staging visible
        bf16x8 af[2][4], bg[2][4];
#pragma unroll
        for (int kh = 0; kh < 2; kh++)
#pragma unroll
            for (int t = 0; t < 4; t++)
                af[kh][t] = *(const bf16x8*)&As[kh * 4096 + (wr * 64 + t * 16 + l16) * 32 + quad * 8];
#pragma unroll
        for (int kh = 0; kh < 2; kh++)
#pragma unroll
            for (int t = 0; t < 4; t++)
                bg[kh][t] = *(const bf16x8*)&Bs[kh * 4096 + (wc * 64 + t * 16 + l16) * 32 + quad * 8];
#pragma unroll
        for (int kh = 0; kh < 2; kh++)
#pragma unroll
            for (int i = 0; i < 4; i++)
#pragma unroll
                for (int j = 0; j < 4; j++)
                    acc[i][j] = __builtin_amdgcn_mfma_f32_16x16x32_bf16(af[kh][i], bg[kh][j], acc[i][j], 0, 0, 0);
        __syncthreads();
    }

    // epilogue: C/D layout col=lane&15, row=quad*4+r (verified m89/m91)
#pragma unroll
    for (int i = 0; i < 4; i++) {
        int gm0 = m0 + wr * 64 + i * 16 + quad * 4;
#pragma unroll
        for (int j = 0; j < 4; j++) {
            int gn = n0 + wc * 64 + j * 16 + l16;
            if (gn >= N) continue;
            float bn = (biasMode == 1) ? bias[gn] : 0.0f;
#pragma unroll
            for (int r = 0; r < 4; r++) {
                int gm = gm0 + r;
                if (gm >= M) continue;
                float v = acc[i][j][r] * alpha + bn;
                if (biasMode == 2) v += bias[gm];
                long idx = (long)bz * sC + (long)gm * ldc + gn;
                if (OUT_BF16) ((u16*)Cm)[idx] = f2bf(v);
                else ((float*)Cm)[idx] = v;
            }
        }
    }
}

// ---------------- row softmax: fp32 in [rows,512] -> bf16 out ----------------
__global__ __launch_bounds__(256) void k_softmax(
    const float* __restrict__ S, u16* __restrict__ P)
{
    long row = blockIdx.x;
    const float* s = S + row * 512;
    u16* p = P + row * 512;
    int tid = threadIdx.x;
    float a = s[tid], b = s[tid + 256];
    float m = fmaxf(a, b);
    for (int off = 32; off; off >>= 1) m = fmaxf(m, __shfl_down(m, off));
    __shared__ float redm[4];
    if ((tid & 63) == 0) redm[tid >> 6] = m;
    __syncthreads();
    m = fmaxf(fmaxf(redm[0], redm[1]), fmaxf(redm[2], redm[3]));
    float ea = __expf(a - m), eb = __expf(b - m);
    float sum = ea + eb;
    for (int off = 32; off; off >>= 1) sum += __shfl_down(sum, off);
    __shared__ float reds[4];
    if ((tid & 63) == 0) reds[tid >> 6] = sum;
    __syncthreads();
    float inv = 1.0f / (reds[0] + reds[1] + reds[2] + reds[3]);
    p[tid] = f2bf(ea * inv);
    p[tid + 256] = f2bf(eb * inv);
}

// ---------------- x = LN(x + s) * g + beta ; also emit bf16 copy ----------------
__global__ __launch_bounds__(256) void k_add_ln(
    float* __restrict__ xf, u16* __restrict__ xb,
    const float* __restrict__ s, int sBroadcast,
    const float* __restrict__ g, const float* __restrict__ beta)
{
    int row = blockIdx.x;             // b*512 + l
    int srow = sBroadcast ? (row & 511) : row;
    float* x = xf + (long)row * 1024;
    u16* xo = xb + (long)row * 1024;
    const float* sp = s + (long)srow * 1024;
    int tid = threadIdx.x;
    float v[4];
    float sum = 0.f, sq = 0.f;
#pragma unroll
    for (int i = 0; i < 4; i++) {
        int idx = tid + i * 256;
        v[i] = x[idx] + sp[idx];
        sum += v[i];
        sq += v[i] * v[i];
    }
    for (int off = 32; off; off >>= 1) {
        sum += __shfl_down(sum, off);
        sq += __shfl_down(sq, off);
    }
    __shared__ float rs[4], rq[4];
    if ((tid & 63) == 0) { rs[tid >> 6] = sum; rq[tid >> 6] = sq; }
    __syncthreads();
    sum = rs[0] + rs[1] + rs[2] + rs[3];
    sq  = rq[0] + rq[1] + rq[2] + rq[3];
    float mean = sum * (1.f / 1024.f);
    float var = sq * (1.f / 1024.f) - mean * mean;
    float rstd = rsqrtf(var + LN_EPS);
#pragma unroll
    for (int i = 0; i < 4; i++) {
        int idx = tid + i * 256;
        float y = (v[i] - mean) * rstd * g[idx] + beta[idx];
        x[idx] = y;
        xo[idx] = f2bf(y);
    }
}

// ---------------- pooled[b][d] = mean_l x[b][l][d] ----------------
__global__ __launch_bounds__(256) void k_pool(
    const float* __restrict__ xf, float* __restrict__ pooled)
{
    int b = blockIdx.x, dchunk = blockIdx.y;
    int t = threadIdx.x & 63, lpart = threadIdx.x >> 6;
    int d = dchunk * 64 + t;
    const float* x = xf + (long)b * 512 * 1024;
    float s = 0.f;
    for (int l = lpart; l < 512; l += 4) s += x[(long)l * 1024 + d];
    __shared__ float red[4][64];
    red[lpart][t] = s;
    __syncthreads();
    if (threadIdx.x < 64) {
        float tot = red[0][threadIdx.x] + red[1][threadIdx.x] + red[2][threadIdx.x] + red[3][threadIdx.x];
        pooled[b * 1024 + dchunk * 64 + threadIdx.x] = tot * (1.f / 512.f);
    }
}

// ---------------- out[b][c] = pooled[b] . wf[:,c] + bf[c] ----------------
__global__ __launch_bounds__(256) void k_head(
    const float* __restrict__ pooled, const float* __restrict__ wf,
    const float* __restrict__ bfin, float* __restrict__ out)
{
    int b = blockIdx.x / 10, c = blockIdx.x % 10;
    const float* p = pooled + b * 1024;
    float s = 0.f;
    for (int d = threadIdx.x; d < 1024; d += 256) s += p[d] * wf[(long)d * 10 + c];
    for (int off = 32; off; off >>= 1) s += __shfl_down(s, off);
    __shared__ float red[4];
    if ((threadIdx.x & 63) == 0) red[threadIdx.x >> 6] = s;
    __syncthreads();
    if (threadIdx.x == 0) out[b * 10 + c] = red[0] + red[1] + red[2] + red[3] + bfin[c];
}

// ---------------- host side ----------------
static void gemm(bool outBf16, const u16* A, long lda, long sA,
                 const u16* B, long ldb, long sB,
                 void* C, long ldc, long sC,
                 int M, int N, int K, const float* bias, int biasMode, float alpha,
                 int batch, hipStream_t st)
{
    dim3 g((N + 127) / 128, (M + 127) / 128, batch);
    if (outBf16)
        k_gemm_nt<true><<<g, 256, 0, st>>>(A, lda, sA, B, ldb, sB, C, ldc, sC, M, N, K, bias, biasMode, alpha);
    else
        k_gemm_nt<false><<<g, 256, 0, st>>>(A, lda, sA, B, ldb, sB, C, ldc, sC, M, N, K, bias, biasMode, alpha);
}

extern "C" void kernel_launch(void* const* d_in, const int* in_sizes, int n_in,
                              void* d_out, int out_size, void* d_ws, size_t ws_size,
                              hipStream_t stream)
{
    const int* ids   = (const int*)d_in[0];
    const float* emb = (const float*)d_in[1];
    const float* pe  = (const float*)d_in[2];
    const float* wq  = (const float*)d_in[3];
    const float* bq  = (const float*)d_in[4];
    const float* wk  = (const float*)d_in[5];
    const float* bk  = (const float*)d_in[6];
    const float* wv  = (const float*)d_in[7];
    const float* bv  = (const float*)d_in[8];
    const float* wo  = (const float*)d_in[9];
    const float* bo  = (const float*)d_in[10];
    const float* w1  = (const float*)d_in[11];
    const float* b1  = (const float*)d_in[12];
    const float* w2  = (const float*)d_in[13];
    const float* b2  = (const float*)d_in[14];
    const float* g1  = (const float*)d_in[15];
    const float* be1 = (const float*)d_in[16];
    const float* g2  = (const float*)d_in[17];
    const float* be2 = (const float*)d_in[18];
    const float* wf  = (const float*)d_in[19];
    const float* bfi = (const float*)d_in[20];
    float* out = (float*)d_out;

    char* base = (char*)d_ws;
    size_t off = 0;
    auto alloc = [&](size_t bytes) {
        char* p = base + off;
        off = (off + bytes + 255) & ~(size_t)255;
        return p;
    };
    float* xf    = (float*)alloc(16UL * 512 * 1024 * 4);   // fp32 residual stream [B,L,D]
    u16*   xb    = (u16*)  alloc(16UL * 512 * 1024 * 2);   // bf16 copy of x
    u16*   wqkvT = (u16*)  alloc(3072UL * 1024 * 2);       // [3072,1024] = wqT;wkT;wvT
    u16*   woT   = (u16*)  alloc(1024UL * 1024 * 2);
    u16*   w1T   = (u16*)  alloc(4096UL * 1024 * 2);       // [F,D]
    u16*   w2T   = (u16*)  alloc(1024UL * 4096 * 2);       // [D,F]
    float* qkvb  = (float*)alloc(3072UL * 4);              // concat(bq,bk,bv)
    u16*   qkv   = (u16*)  alloc(512UL * 3072 * 2);        // [L, 3*D] = q|k|v
    u16*   vT    = (u16*)  alloc(1024UL * 512 * 2);        // v transposed [D,L]
    float* sc    = (float*)alloc(16UL * 512 * 512 * 4);    // scores [H,L,L]
    u16*   P     = (u16*)  alloc(16UL * 512 * 512 * 2);    // softmax probs bf16
    u16*   Ob    = (u16*)  alloc(512UL * 1024 * 2);        // attn context bf16 [L,D]
    float* src2  = (float*)alloc(512UL * 1024 * 4);
    u16*   Hb    = (u16*)  alloc(8192UL * 4096 * 2);       // FFN hidden bf16
    float* ffb   = (float*)alloc(8192UL * 1024 * 4);
    float* pooled = (float*)alloc(16UL * 1024 * 4);

    // weight conversion (every launch: ws re-poisoned)
    k_transpose_bf16<<<dim3(32, 32), 256, 0, stream>>>(wq, wqkvT + 0,            1024, 1024, 1024);
    k_transpose_bf16<<<dim3(32, 32), 256, 0, stream>>>(wk, wqkvT + 1024UL * 1024, 1024, 1024, 1024);
    k_transpose_bf16<<<dim3(32, 32), 256, 0, stream>>>(wv, wqkvT + 2048UL * 1024, 1024, 1024, 1024);
    k_transpose_bf16<<<dim3(32, 32), 256, 0, stream>>>(wo, woT, 1024, 1024, 1024);
    k_transpose_bf16<<<dim3(128, 32), 256, 0, stream>>>(w1, w1T, 1024, 4096, 1024);
    k_transpose_bf16<<<dim3(32, 128), 256, 0, stream>>>(w2, w2T, 4096, 1024, 4096);
    k_concat3<<<12, 256, 0, stream>>>(bq, bk, bv, qkvb);

    k_embed<<<8192, 256, 0, stream>>>(ids, emb, pe, xf, xb);

    const u16* qb   = qkv;            // [512,1024] with row stride 3072
    const u16* kbuf = qkv + 1024;
    for (int layer = 0; layer < 6; layer++) {
        // fused q|k|v for batch 0: [512,3072] = xb[0:512] @ wqkvT^T + qkvb
        gemm(true, xb, 1024, 0, wqkvT, 1024, 0, qkv, 3072, 0, 512, 3072, 1024, qkvb, 1, 1.f, 1, stream);
        // vT[d][l] from v part of qkv
        k_transpose_bb<<<dim3(32, 16), 256, 0, stream>>>(qkv + 2048, 3072, vT, 512);
        // scores[h] = Q_h . K_h^T * 0.125  (batched over heads; per-head col offset h*64)
        gemm(false, qb, 3072, 64, kbuf, 3072, 64, sc, 512, 512L * 512, 512, 512, 64, nullptr, 0, 0.125f, 16, stream);
        k_softmax<<<16 * 512, 256, 0, stream>>>(sc, P);
        // O_h = P_h . V_h  (B operand = vT rows h*64..h*64+63)
        gemm(true, P, 512, 512L * 512, vT, 512, 64L * 512, Ob, 1024, 64, 512, 64, 512, nullptr, 0, 1.f, 16, stream);
        // src2 = O . wo + bo
        gemm(false, Ob, 1024, 0, woT, 1024, 0, src2, 1024, 0, 512, 1024, 1024, bo, 1, 1.f, 1, stream);
        k_add_ln<<<8192, 256, 0, stream>>>(xf, xb, src2, 1, g1, be1);
        // FFN
        gemm(true, xb, 1024, 0, w1T, 1024, 0, Hb, 4096, 0, 8192, 4096, 1024, b1, 1, 1.f, 1, stream);
        gemm(false, Hb, 4096, 0, w2T, 4096, 0, ffb, 1024, 0, 8192, 1024, 4096, b2, 1, 1.f, 1, stream);
        k_add_ln<<<8192, 256, 0, stream>>>(xf, xb, ffb, 0, g2, be2);
    }

    k_pool<<<dim3(16, 16), 256, 0, stream>>>(xf, pooled);
    k_head<<<160, 256, 0, stream>>>(pooled, wf, bfi, out);
}

// Round 4
// 2165.836 us; speedup vs baseline: 1.8017x; 1.0618x over previous
//
#include <hip/hip_runtime.h>

typedef unsigned short u16;
typedef unsigned int u32;
typedef __bf16 bf16x8 __attribute__((ext_vector_type(8)));
typedef float f32x4 __attribute__((ext_vector_type(4)));

#define LN_EPS 1e-5f
#define L2E 1.44269504f

__device__ __forceinline__ u16 f2bf(float f) {
    u32 u = __float_as_uint(f);
    u += 0x7fffu + ((u >> 16) & 1u);
    return (u16)(u >> 16);
}

// async global->LDS, 16B per lane; lds base must be wave-uniform (HW: base + lane*16)
#define ASYNC_CP16(g, l)                                                      \
    __builtin_amdgcn_global_load_lds(                                         \
        (const __attribute__((address_space(1))) u32*)(g),                    \
        (__attribute__((address_space(3))) u32*)(l), 16, 0, 0)

// ---------------- transpose f32 -> bf16 (out[c][r] = in[r][c]) ----------------
__global__ __launch_bounds__(256) void k_transpose_bf16(
    const float* __restrict__ in, u16* __restrict__ out, int R, int C, long ldo)
{
    __shared__ float tile[32][33];
    int c0 = blockIdx.x * 32, r0 = blockIdx.y * 32;
    int tx = threadIdx.x & 31, ty = threadIdx.x >> 5;
#pragma unroll
    for (int i = 0; i < 4; i++)
        tile[ty + 8 * i][tx] = in[(long)(r0 + ty + 8 * i) * C + c0 + tx];
    __syncthreads();
#pragma unroll
    for (int i = 0; i < 4; i++)
        out[(long)(c0 + ty + 8 * i) * ldo + r0 + tx] = f2bf(tile[tx][ty + 8 * i]);
}

// ---------------- transpose bf16 -> bf16 (out[c][r] = in[r][c]) ----------------
__global__ __launch_bounds__(256) void k_transpose_bb(
    const u16* __restrict__ in, long ldi, u16* __restrict__ out, long ldo)
{
    __shared__ u16 tile[32][33];
    int c0 = blockIdx.x * 32, r0 = blockIdx.y * 32;
    int tx = threadIdx.x & 31, ty = threadIdx.x >> 5;
#pragma unroll
    for (int i = 0; i < 4; i++)
        tile[ty + 8 * i][tx] = in[(long)(r0 + ty + 8 * i) * ldi + c0 + tx];
    __syncthreads();
#pragma unroll
    for (int i = 0; i < 4; i++)
        out[(long)(c0 + ty + 8 * i) * ldo + r0 + tx] = tile[tx][ty + 8 * i];
}

// ---------------- concat 3 bias vectors [1024] -> [3072] ----------------
__global__ __launch_bounds__(256) void k_concat3(
    const float* __restrict__ a, const float* __restrict__ b,
    const float* __restrict__ c, float* __restrict__ o)
{
    int i = blockIdx.x * 256 + threadIdx.x;
    float v = (i < 1024) ? a[i] : (i < 2048 ? b[i - 1024] : c[i - 2048]);
    o[i] = v;
}

// ---------------- embedding: x = emb[id]*32 + pe ----------------
__global__ __launch_bounds__(256) void k_embed(
    const int* __restrict__ ids, const float* __restrict__ emb,
    const float* __restrict__ pe, float* __restrict__ xf, u16* __restrict__ xb)
{
    int row = blockIdx.x;          // b*512 + l
    int l = row & 511;
    long id = (long)ids[row];
    const float* e = emb + id * 1024;
    const float* p = pe + (long)l * 1024;
    float* xo = xf + (long)row * 1024;
    u16* xbo = xb + (long)row * 1024;
#pragma unroll
    for (int i = 0; i < 4; i++) {
        int idx = threadIdx.x + 256 * i;
        float v = e[idx] * 32.0f + p[idx];
        xo[idx] = v;
        xbo[idx] = f2bf(v);
    }
}

// ---------------- bf16 MFMA GEMM, NT form: C[m][n] = alpha * sum_k A[m][k]*B[n][k] + bias ----
// A: [M,K] bf16 row-major (lda), B: [N,K] bf16 row-major (ldb). Batched via blockIdx.z.
// biasMode: 0=none, 1=bias[n], 2=bias[m].
template <bool OUT_BF16>
__global__ __launch_bounds__(256) void k_gemm_nt(
    const u16* __restrict__ A, long lda, long sA,
    const u16* __restrict__ B, long ldb, long sB,
    void* __restrict__ Cm, long ldc, long sC,
    int M, int N, int K,
    const float* __restrict__ bias, int biasMode, float alpha)
{
    __shared__ u16 As[2 * 128 * 32];   // [kh][row][32], unpadded per plane
    __shared__ u16 Bs[2 * 128 * 32];
    int bz = blockIdx.z;
    A += (long)bz * sA;
    B += (long)bz * sB;
    int m0 = blockIdx.y * 128, n0 = blockIdx.x * 128;
    int tid = threadIdx.x;
    int lane = tid & 63, wid = tid >> 6;
    int wr = wid >> 1, wc = wid & 1;
    int quad = lane >> 4, l16 = lane & 15;

    f32x4 acc[4][4];
#pragma unroll
    for (int i = 0; i < 4; i++)
#pragma unroll
        for (int j = 0; j < 4; j++) acc[i][j] = {0.f, 0.f, 0.f, 0.f};

    int rloc0 = (wid * 2 + 0) * 16 + (lane >> 2);
    int rloc1 = (wid * 2 + 1) * 16 + (lane >> 2);
    int seg = (lane & 3) * 8;
    u16* a00 = &As[(wid * 2 + 0) * 512];
    u16* a01 = &As[(wid * 2 + 1) * 512];
    u16* a10 = &As[4096 + (wid * 2 + 0) * 512];
    u16* a11 = &As[4096 + (wid * 2 + 1) * 512];
    u16* b00 = &Bs[(wid * 2 + 0) * 512];
    u16* b01 = &Bs[(wid * 2 + 1) * 512];
    u16* b10 = &Bs[4096 + (wid * 2 + 0) * 512];
    u16* b11 = &Bs[4096 + (wid * 2 + 1) * 512];
    int gmA0 = min(m0 + rloc0, M - 1), gmA1 = min(m0 + rloc1, M - 1);
    int gnB0 = min(n0 + rloc0, N - 1), gnB1 = min(n0 + rloc1, N - 1);
    const u16* pA0 = A + (long)gmA0 * lda + seg;
    const u16* pA1 = A + (long)gmA1 * lda + seg;
    const u16* pB0 = B + (long)gnB0 * ldb + seg;
    const u16* pB1 = B + (long)gnB1 * ldb + seg;

    for (int kb = 0; kb < K; kb += 64) {
        ASYNC_CP16(pA0 + kb,      a00);
        ASYNC_CP16(pA1 + kb,      a01);
        ASYNC_CP16(pA0 + kb + 32, a10);
        ASYNC_CP16(pA1 + kb + 32, a11);
        ASYNC_CP16(pB0 + kb,      b00);
        ASYNC_CP16(pB1 + kb,      b01);
        ASYNC_CP16(pB0 + kb + 32, b10);
        ASYNC_CP16(pB1 + kb + 32, b11);
        __syncthreads();
        bf16x8 af[2][4], bg[2][4];
#pragma unroll
        for (int kh = 0; kh < 2; kh++)
#pragma unroll
            for (int t = 0; t < 4; t++)
                af[kh][t] = *(const bf16x8*)&As[kh * 4096 + (wr * 64 + t * 16 + l16) * 32 + quad * 8];
#pragma unroll
        for (int kh = 0; kh < 2; kh++)
#pragma unroll
            for (int t = 0; t < 4; t++)
                bg[kh][t] = *(const bf16x8*)&Bs[kh * 4096 + (wc * 64 + t * 16 + l16) * 32 + quad * 8];
#pragma unroll
        for (int kh = 0; kh < 2; kh++)
#pragma unroll
            for (int i = 0; i < 4; i++)
#pragma unroll
                for (int j = 0; j < 4; j++)
                    acc[i][j] = __builtin_amdgcn_mfma_f32_16x16x32_bf16(af[kh][i], bg[kh][j], acc[i][j], 0, 0, 0);
        __syncthreads();
    }

#pragma unroll
    for (int i = 0; i < 4; i++) {
        int gm0 = m0 + wr * 64 + i * 16 + quad * 4;
#pragma unroll
        for (int j = 0; j < 4; j++) {
            int gn = n0 + wc * 64 + j * 16 + l16;
            if (gn >= N) continue;
            float bn = (biasMode == 1) ? bias[gn] : 0.0f;
#pragma unroll
            for (int r = 0; r < 4; r++) {
                int gm = gm0 + r;
                if (gm >= M) continue;
                float v = acc[i][j][r] * alpha + bn;
                if (biasMode == 2) v += bias[gm];
                long idx = (long)bz * sC + (long)gm * ldc + gn;
                if (OUT_BF16) ((u16*)Cm)[idx] = f2bf(v);
                else ((float*)Cm)[idx] = v;
            }
        }
    }
}

// ---------------- fused attention: scores+softmax+PV for one (head, 32-q-row) block ---
// qkv [512,3072] bf16 (q|k|v); vT [1024,512] bf16; Ob [512,1024] bf16.
// 128 threads = 2 waves, each wave owns 16 q-rows. K/V tiles (64 keys) double-buffered
// in LDS via global_load_lds; online softmax in registers; P via stride-72 LDS tile.
__global__ __launch_bounds__(128) void k_attn(
    const u16* __restrict__ qkv, const u16* __restrict__ vT, u16* __restrict__ Ob)
{
    __shared__ u16 Ks[2][4096];   // plane layout: idx(key,d) = (d>>5)*2048 + key*32 + (d&31)
    __shared__ u16 Vs[2][4096];   // idx(d,key)   = (key>>5)*2048 + d*32 + (key&31)
    __shared__ u16 Pl[32 * 72];   // [q_local][72]; 72*2B = 144B rows -> 16B-aligned
    int qb = blockIdx.x, h = blockIdx.y;
    int tid = threadIdx.x;
    int w = tid >> 6, lane = tid & 63;
    int quad = lane >> 4, l16 = lane & 15;

    // Q A-frags (m = l16): q-row = qb*32 + w*16 + l16
    int qrow = qb * 32 + w * 16 + l16;
    bf16x8 aq[2];
#pragma unroll
    for (int c = 0; c < 2; c++)
        aq[c] = *(const bf16x8*)&qkv[(long)qrow * 3072 + h * 64 + c * 32 + quad * 8];

    f32x4 acc_o[4];
#pragma unroll
    for (int j = 0; j < 4; j++) acc_o[j] = {0.f, 0.f, 0.f, 0.f};
    float mrow[4], lrow[4];
#pragma unroll
    for (int r = 0; r < 4; r++) { mrow[r] = -1e30f; lrow[r] = 0.f; }

    // staging: chunk c = rr*2 + w in [0,8): loc = (c&3)*16 + lane/4, off8 = (c>>2)*32 + (lane%4)*8
    // K chunk -> Ks[...][c*512 + lane*8] ; V chunk likewise (loc=d for V, off8=key)
    {
        int kt = 0;
#pragma unroll
        for (int rr = 0; rr < 4; rr++) {
            int c = rr * 2 + w;
            int loc = (c & 3) * 16 + (lane >> 2);
            int off8 = ((c >> 2) << 5) + (lane & 3) * 8;
            ASYNC_CP16(&qkv[(long)(kt * 64 + loc) * 3072 + 1024 + h * 64 + off8], &Ks[0][c * 512]);
            ASYNC_CP16(&vT[(long)(h * 64 + loc) * 512 + kt * 64 + off8], &Vs[0][c * 512]);
        }
    }
    __syncthreads();

    for (int kt = 0; kt < 8; kt++) {
        int buf = kt & 1;
        if (kt < 7) {
            int nb = buf ^ 1, ktn = kt + 1;
#pragma unroll
            for (int rr = 0; rr < 4; rr++) {
                int c = rr * 2 + w;
                int loc = (c & 3) * 16 + (lane >> 2);
                int off8 = ((c >> 2) << 5) + (lane & 3) * 8;
                ASYNC_CP16(&qkv[(long)(ktn * 64 + loc) * 3072 + 1024 + h * 64 + off8], &Ks[nb][c * 512]);
                ASYNC_CP16(&vT[(long)(h * 64 + loc) * 512 + ktn * 64 + off8], &Vs[nb][c * 512]);
            }
        }
        // S = Q.K^T (raw), C/D: col(key)=l16, row(q)=quad*4+r
        f32x4 s[4];
#pragma unroll
        for (int ss = 0; ss < 4; ss++) {
            s[ss] = {0.f, 0.f, 0.f, 0.f};
#pragma unroll
            for (int c = 0; c < 2; c++) {
                bf16x8 bk = *(const bf16x8*)&Ks[buf][c * 2048 + (ss * 16 + l16) * 32 + quad * 8];
                s[ss] = __builtin_amdgcn_mfma_f32_16x16x32_bf16(aq[c], bk, s[ss], 0, 0, 0);
            }
        }
        // scale + online softmax
        float mt[4];
#pragma unroll
        for (int r = 0; r < 4; r++) {
#pragma unroll
            for (int ss = 0; ss < 4; ss++) s[ss][r] *= 0.125f;
            mt[r] = fmaxf(fmaxf(s[0][r], s[1][r]), fmaxf(s[2][r], s[3][r]));
        }
#pragma unroll
        for (int mask = 1; mask < 16; mask <<= 1)
#pragma unroll
            for (int r = 0; r < 4; r++) mt[r] = fmaxf(mt[r], __shfl_xor(mt[r], mask));
        float al[4], rsum[4];
#pragma unroll
        for (int r = 0; r < 4; r++) {
            float mn = fmaxf(mrow[r], mt[r]);
            al[r] = exp2f((mrow[r] - mn) * L2E);
            mrow[r] = mn;
            rsum[r] = 0.f;
#pragma unroll
            for (int ss = 0; ss < 4; ss++) {
                float p = exp2f((s[ss][r] - mn) * L2E);
                s[ss][r] = p;
                rsum[r] += p;
            }
        }
#pragma unroll
        for (int mask = 1; mask < 16; mask <<= 1)
#pragma unroll
            for (int r = 0; r < 4; r++) rsum[r] += __shfl_xor(rsum[r], mask);
#pragma unroll
        for (int r = 0; r < 4; r++) lrow[r] = lrow[r] * al[r] + rsum[r];
#pragma unroll
        for (int j = 0; j < 4; j++)
#pragma unroll
            for (int r = 0; r < 4; r++) acc_o[j][r] *= al[r];
        // P -> LDS (own wave's rows only; compiler orders write->read via lgkmcnt)
#pragma unroll
        for (int ss = 0; ss < 4; ss++)
#pragma unroll
            for (int r = 0; r < 4; r++)
                Pl[(w * 16 + quad * 4 + r) * 72 + ss * 16 + l16] = f2bf(s[ss][r]);
        // O += P.V : A = P[q][k-contig], B = vT[d][k-contig]
#pragma unroll
        for (int kc = 0; kc < 2; kc++) {
            bf16x8 ap = *(const bf16x8*)&Pl[(w * 16 + l16) * 72 + kc * 32 + quad * 8];
#pragma unroll
            for (int j = 0; j < 4; j++) {
                bf16x8 bv = *(const bf16x8*)&Vs[buf][kc * 2048 + (j * 16 + l16) * 32 + quad * 8];
                acc_o[j] = __builtin_amdgcn_mfma_f32_16x16x32_bf16(ap, bv, acc_o[j], 0, 0, 0);
            }
        }
        __syncthreads();   // prefetch visible + buffers safe to reuse
    }

#pragma unroll
    for (int r = 0; r < 4; r++) {
        float inv = 1.0f / lrow[r];
        int gq = qb * 32 + w * 16 + quad * 4 + r;
#pragma unroll
        for (int j = 0; j < 4; j++)
            Ob[(long)gq * 1024 + h * 64 + j * 16 + l16] = f2bf(acc_o[j][r] * inv);
    }
}

// ---------------- x = LN(x + s) * g + beta ; also emit bf16 copy ----------------
__global__ __launch_bounds__(256) void k_add_ln(
    float* __restrict__ xf, u16* __restrict__ xb,
    const float* __restrict__ s, int sBroadcast,
    const float* __restrict__ g, const float* __restrict__ beta)
{
    int row = blockIdx.x;             // b*512 + l
    int srow = sBroadcast ? (row & 511) : row;
    float* x = xf + (long)row * 1024;
    u16* xo = xb + (long)row * 1024;
    const float* sp = s + (long)srow * 1024;
    int tid = threadIdx.x;
    float v[4];
    float sum = 0.f, sq = 0.f;
#pragma unroll
    for (int i = 0; i < 4; i++) {
        int idx = tid + i * 256;
        v[i] = x[idx] + sp[idx];
        sum += v[i];
        sq += v[i] * v[i];
    }
    for (int off = 32; off; off >>= 1) {
        sum += __shfl_down(sum, off);
        sq += __shfl_down(sq, off);
    }
    __shared__ float rs[4], rq[4];
    if ((tid & 63) == 0) { rs[tid >> 6] = sum; rq[tid >> 6] = sq; }
    __syncthreads();
    sum = rs[0] + rs[1] + rs[2] + rs[3];
    sq  = rq[0] + rq[1] + rq[2] + rq[3];
    float mean = sum * (1.f / 1024.f);
    float var = sq * (1.f / 1024.f) - mean * mean;
    float rstd = rsqrtf(var + LN_EPS);
#pragma unroll
    for (int i = 0; i < 4; i++) {
        int idx = tid + i * 256;
        float y = (v[i] - mean) * rstd * g[idx] + beta[idx];
        x[idx] = y;
        xo[idx] = f2bf(y);
    }
}

// ---------------- pooled[b][d] = mean_l x[b][l][d] ----------------
__global__ __launch_bounds__(256) void k_pool(
    const float* __restrict__ xf, float* __restrict__ pooled)
{
    int b = blockIdx.x, dchunk = blockIdx.y;
    int t = threadIdx.x & 63, lpart = threadIdx.x >> 6;
    int d = dchunk * 64 + t;
    const float* x = xf + (long)b * 512 * 1024;
    float s = 0.f;
    for (int l = lpart; l < 512; l += 4) s += x[(long)l * 1024 + d];
    __shared__ float red[4][64];
    red[lpart][t] = s;
    __syncthreads();
    if (threadIdx.x < 64) {
        float tot = red[0][threadIdx.x] + red[1][threadIdx.x] + red[2][threadIdx.x] + red[3][threadIdx.x];
        pooled[b * 1024 + dchunk * 64 + threadIdx.x] = tot * (1.f / 512.f);
    }
}

// ---------------- out[b][c] = pooled[b] . wf[:,c] + bf[c] ----------------
__global__ __launch_bounds__(256) void k_head(
    const float* __restrict__ pooled, const float* __restrict__ wf,
    const float* __restrict__ bfin, float* __restrict__ out)
{
    int b = blockIdx.x / 10, c = blockIdx.x % 10;
    const float* p = pooled + b * 1024;
    float s = 0.f;
    for (int d = threadIdx.x; d < 1024; d += 256) s += p[d] * wf[(long)d * 10 + c];
    for (int off = 32; off; off >>= 1) s += __shfl_down(s, off);
    __shared__ float red[4];
    if ((threadIdx.x & 63) == 0) red[threadIdx.x >> 6] = s;
    __syncthreads();
    if (threadIdx.x == 0) out[b * 10 + c] = red[0] + red[1] + red[2] + red[3] + bfin[c];
}

// ---------------- host side ----------------
static void gemm(bool outBf16, const u16* A, long lda, long sA,
                 const u16* B, long ldb, long sB,
                 void* C, long ldc, long sC,
                 int M, int N, int K, const float* bias, int biasMode, float alpha,
                 int batch, hipStream_t st)
{
    dim3 g((N + 127) / 128, (M + 127) / 128, batch);
    if (outBf16)
        k_gemm_nt<true><<<g, 256, 0, st>>>(A, lda, sA, B, ldb, sB, C, ldc, sC, M, N, K, bias, biasMode, alpha);
    else
        k_gemm_nt<false><<<g, 256, 0, st>>>(A, lda, sA, B, ldb, sB, C, ldc, sC, M, N, K, bias, biasMode, alpha);
}

extern "C" void kernel_launch(void* const* d_in, const int* in_sizes, int n_in,
                              void* d_out, int out_size, void* d_ws, size_t ws_size,
                              hipStream_t stream)
{
    const int* ids   = (const int*)d_in[0];
    const float* emb = (const float*)d_in[1];
    const float* pe  = (const float*)d_in[2];
    const float* wq  = (const float*)d_in[3];
    const float* bq  = (const float*)d_in[4];
    const float* wk  = (const float*)d_in[5];
    const float* bk  = (const float*)d_in[6];
    const float* wv  = (const float*)d_in[7];
    const float* bv  = (const float*)d_in[8];
    const float* wo  = (const float*)d_in[9];
    const float* bo  = (const float*)d_in[10];
    const float* w1  = (const float*)d_in[11];
    const float* b1  = (const float*)d_in[12];
    const float* w2  = (const float*)d_in[13];
    const float* b2  = (const float*)d_in[14];
    const float* g1  = (const float*)d_in[15];
    const float* be1 = (const float*)d_in[16];
    const float* g2  = (const float*)d_in[17];
    const float* be2 = (const float*)d_in[18];
    const float* wf  = (const float*)d_in[19];
    const float* bfi = (const float*)d_in[20];
    float* out = (float*)d_out;

    char* base = (char*)d_ws;
    size_t off = 0;
    auto alloc = [&](size_t bytes) {
        char* p = base + off;
        off = (off + bytes + 255) & ~(size_t)255;
        return p;
    };
    float* xf    = (float*)alloc(16UL * 512 * 1024 * 4);   // fp32 residual stream [B,L,D]
    u16*   xb    = (u16*)  alloc(16UL * 512 * 1024 * 2);   // bf16 copy of x
    u16*   wqkvT = (u16*)  alloc(3072UL * 1024 * 2);       // [3072,1024] = wqT;wkT;wvT
    u16*   woT   = (u16*)  alloc(1024UL * 1024 * 2);
    u16*   w1T   = (u16*)  alloc(4096UL * 1024 * 2);       // [F,D]
    u16*   w2T   = (u16*)  alloc(1024UL * 4096 * 2);       // [D,F]
    float* qkvb  = (float*)alloc(3072UL * 4);              // concat(bq,bk,bv)
    u16*   qkv   = (u16*)  alloc(512UL * 3072 * 2);        // [L, 3*D] = q|k|v
    u16*   vT    = (u16*)  alloc(1024UL * 512 * 2);        // v transposed [D,L]
    u16*   Ob    = (u16*)  alloc(512UL * 1024 * 2);        // attn context bf16 [L,D]
    float* src2  = (float*)alloc(512UL * 1024 * 4);
    u16*   Hb    = (u16*)  alloc(8192UL * 4096 * 2);       // FFN hidden bf16
    float* ffb   = (float*)alloc(8192UL * 1024 * 4);
    float* pooled = (float*)alloc(16UL * 1024 * 4);

    // weight conversion (every launch: ws re-poisoned)
    k_transpose_bf16<<<dim3(32, 32), 256, 0, stream>>>(wq, wqkvT + 0,             1024, 1024, 1024);
    k_transpose_bf16<<<dim3(32, 32), 256, 0, stream>>>(wk, wqkvT + 1024UL * 1024, 1024, 1024, 1024);
    k_transpose_bf16<<<dim3(32, 32), 256, 0, stream>>>(wv, wqkvT + 2048UL * 1024, 1024, 1024, 1024);
    k_transpose_bf16<<<dim3(32, 32), 256, 0, stream>>>(wo, woT, 1024, 1024, 1024);
    k_transpose_bf16<<<dim3(128, 32), 256, 0, stream>>>(w1, w1T, 1024, 4096, 1024);
    k_transpose_bf16<<<dim3(32, 128), 256, 0, stream>>>(w2, w2T, 4096, 1024, 4096);
    k_concat3<<<12, 256, 0, stream>>>(bq, bk, bv, qkvb);

    k_embed<<<8192, 256, 0, stream>>>(ids, emb, pe, xf, xb);

    for (int layer = 0; layer < 6; layer++) {
        // fused q|k|v for batch 0: [512,3072] = xb[0:512] @ wqkvT^T + qkvb
        gemm(true, xb, 1024, 0, wqkvT, 1024, 0, qkv, 3072, 0, 512, 3072, 1024, qkvb, 1, 1.f, 1, stream);
        // vT[d][l] from v part of qkv
        k_transpose_bb<<<dim3(32, 16), 256, 0, stream>>>(qkv + 2048, 3072, vT, 512);
        // fused scores+softmax+PV
        k_attn<<<dim3(16, 16), 128, 0, stream>>>(qkv, vT, Ob);
        // src2 = O . wo + bo
        gemm(false, Ob, 1024, 0, woT, 1024, 0, src2, 1024, 0, 512, 1024, 1024, bo, 1, 1.f, 1, stream);
        k_add_ln<<<8192, 256, 0, stream>>>(xf, xb, src2, 1, g1, be1);
        // FFN
        gemm(true, xb, 1024, 0, w1T, 1024, 0, Hb, 4096, 0, 8192, 4096, 1024, b1, 1, 1.f, 1, stream);
        gemm(false, Hb, 4096, 0, w2T, 4096, 0, ffb, 1024, 0, 8192, 1024, 4096, b2, 1, 1.f, 1, stream);
        k_add_ln<<<8192, 256, 0, stream>>>(xf, xb, ffb, 0, g2, be2);
    }

    k_pool<<<dim3(16, 16), 256, 0, stream>>>(xf, pooled);
    k_head<<<160, 256, 0, stream>>>(pooled, wf, bfi, out);
}

// Round 5
// 1900.730 us; speedup vs baseline: 2.0530x; 1.1395x over previous
//
#include <hip/hip_runtime.h>

typedef unsigned short u16;
typedef unsigned int u32;
typedef __bf16 bf16x8 __attribute__((ext_vector_type(8)));
typedef float f32x4 __attribute__((ext_vector_type(4)));

#define LN_EPS 1e-5f
#define L2E 1.44269504f

__device__ __forceinline__ u16 f2bf(float f) {
    u32 u = __float_as_uint(f);
    u += 0x7fffu + ((u >> 16) & 1u);
    return (u16)(u >> 16);
}
__device__ __forceinline__ float bf2f(u16 v) {
    return __uint_as_float(((u32)v) << 16);
}

// async global->LDS, 16B per lane; lds base must be wave-uniform (HW: base + lane*16)
#define ASYNC_CP16(g, l)                                                      \
    __builtin_amdgcn_global_load_lds(                                         \
        (const __attribute__((address_space(1))) u32*)(g),                    \
        (__attribute__((address_space(3))) u32*)(l), 16, 0, 0)

// ---------------- transpose f32 -> bf16 (out[c][r] = in[r][c]) ----------------
__global__ __launch_bounds__(256) void k_transpose_bf16(
    const float* __restrict__ in, u16* __restrict__ out, int R, int C, long ldo)
{
    __shared__ float tile[32][33];
    int c0 = blockIdx.x * 32, r0 = blockIdx.y * 32;
    int tx = threadIdx.x & 31, ty = threadIdx.x >> 5;
#pragma unroll
    for (int i = 0; i < 4; i++)
        tile[ty + 8 * i][tx] = in[(long)(r0 + ty + 8 * i) * C + c0 + tx];
    __syncthreads();
#pragma unroll
    for (int i = 0; i < 4; i++)
        out[(long)(c0 + ty + 8 * i) * ldo + r0 + tx] = f2bf(tile[tx][ty + 8 * i]);
}

// ---------------- transpose bf16 -> bf16 (out[c][r] = in[r][c]) ----------------
__global__ __launch_bounds__(256) void k_transpose_bb(
    const u16* __restrict__ in, long ldi, u16* __restrict__ out, long ldo)
{
    __shared__ u16 tile[32][33];
    int c0 = blockIdx.x * 32, r0 = blockIdx.y * 32;
    int tx = threadIdx.x & 31, ty = threadIdx.x >> 5;
#pragma unroll
    for (int i = 0; i < 4; i++)
        tile[ty + 8 * i][tx] = in[(long)(r0 + ty + 8 * i) * ldi + c0 + tx];
    __syncthreads();
#pragma unroll
    for (int i = 0; i < 4; i++)
        out[(long)(c0 + ty + 8 * i) * ldo + r0 + tx] = tile[tx][ty + 8 * i];
}

// ---------------- concat 3 bias vectors [1024] -> [3072] ----------------
__global__ __launch_bounds__(256) void k_concat3(
    const float* __restrict__ a, const float* __restrict__ b,
    const float* __restrict__ c, float* __restrict__ o)
{
    int i = blockIdx.x * 256 + threadIdx.x;
    float v = (i < 1024) ? a[i] : (i < 2048 ? b[i - 1024] : c[i - 2048]);
    o[i] = v;
}

// ---------------- embedding: xb = bf16(emb[id]*32 + pe) ----------------
__global__ __launch_bounds__(256) void k_embed(
    const int* __restrict__ ids, const float* __restrict__ emb,
    const float* __restrict__ pe, u16* __restrict__ xb)
{
    int row = blockIdx.x;          // b*512 + l
    int l = row & 511;
    long id = (long)ids[row];
    const float* e = emb + id * 1024;
    const float* p = pe + (long)l * 1024;
    u16* xbo = xb + (long)row * 1024;
    int d0 = threadIdx.x * 4;
    float4 ev = *(const float4*)&e[d0];
    float4 pv = *(const float4*)&p[d0];
    ushort4 o;
    o.x = f2bf(ev.x * 32.0f + pv.x);
    o.y = f2bf(ev.y * 32.0f + pv.y);
    o.z = f2bf(ev.z * 32.0f + pv.z);
    o.w = f2bf(ev.w * 32.0f + pv.w);
    *(ushort4*)&xbo[d0] = o;
}

// ---------------- bf16 MFMA GEMM, NT form: C[m][n] = alpha * sum_k A[m][k]*B[n][k] + bias ----
// A: [M,K] bf16 row-major (lda), B: [N,K] bf16 row-major (ldb). Batched via blockIdx.z.
// biasMode: 0=none, 1=bias[n], 2=bias[m]. Tile TM x TN, BK=64, 4 waves (2x2).
template <int TM, int TN, bool OUT_BF16>
__global__ __launch_bounds__(256) void k_gemm_nt(
    const u16* __restrict__ A, long lda, long sA,
    const u16* __restrict__ B, long ldb, long sB,
    void* __restrict__ Cm, long ldc, long sC,
    int M, int N, int K,
    const float* __restrict__ bias, int biasMode, float alpha)
{
    constexpr int FM = TM / 32;     // m-frags per wave
    constexpr int FN = TN / 32;     // n-frags per wave
    constexpr int CPA = TM / 64;    // A chunks per wave per K-plane
    constexpr int CPB = TN / 64;
    __shared__ u16 As[2 * TM * 32];
    __shared__ u16 Bs[2 * TN * 32];
    int bz = blockIdx.z;
    A += (long)bz * sA;
    B += (long)bz * sB;
    int m0 = blockIdx.y * TM, n0 = blockIdx.x * TN;
    int tid = threadIdx.x;
    int lane = tid & 63, wid = tid >> 6;
    int wr = wid >> 1, wc = wid & 1;
    int quad = lane >> 4, l16 = lane & 15;

    f32x4 acc[FM][FN];
#pragma unroll
    for (int i = 0; i < FM; i++)
#pragma unroll
        for (int j = 0; j < FN; j++) acc[i][j] = {0.f, 0.f, 0.f, 0.f};

    // staging: chunk = 16 rows x 32 k (1KB); lane l -> row c*16 + l/4, k-seg (l%4)*8
    int seg = (lane & 3) * 8;
    const u16* pA[CPA]; u16* lA[2][CPA];
    const u16* pB[CPB]; u16* lB[2][CPB];
#pragma unroll
    for (int i = 0; i < CPA; i++) {
        int c = wid * CPA + i;
        int gm = min(m0 + c * 16 + (lane >> 2), M - 1);
        pA[i] = A + (long)gm * lda + seg;
        lA[0][i] = &As[c * 512];
        lA[1][i] = &As[TM * 32 + c * 512];
    }
#pragma unroll
    for (int i = 0; i < CPB; i++) {
        int c = wid * CPB + i;
        int gn = min(n0 + c * 16 + (lane >> 2), N - 1);
        pB[i] = B + (long)gn * ldb + seg;
        lB[0][i] = &Bs[c * 512];
        lB[1][i] = &Bs[TN * 32 + c * 512];
    }

    for (int kb = 0; kb < K; kb += 64) {
#pragma unroll
        for (int kh = 0; kh < 2; kh++) {
#pragma unroll
            for (int i = 0; i < CPA; i++) ASYNC_CP16(pA[i] + kb + kh * 32, lA[kh][i]);
#pragma unroll
            for (int i = 0; i < CPB; i++) ASYNC_CP16(pB[i] + kb + kh * 32, lB[kh][i]);
        }
        __syncthreads();
        bf16x8 af[2][FM], bg[2][FN];
#pragma unroll
        for (int kh = 0; kh < 2; kh++)
#pragma unroll
            for (int t = 0; t < FM; t++)
                af[kh][t] = *(const bf16x8*)&As[kh * TM * 32 + (wr * (TM / 2) + t * 16 + l16) * 32 + quad * 8];
#pragma unroll
        for (int kh = 0; kh < 2; kh++)
#pragma unroll
            for (int t = 0; t < FN; t++)
                bg[kh][t] = *(const bf16x8*)&Bs[kh * TN * 32 + (wc * (TN / 2) + t * 16 + l16) * 32 + quad * 8];
#pragma unroll
        for (int kh = 0; kh < 2; kh++)
#pragma unroll
            for (int i = 0; i < FM; i++)
#pragma unroll
                for (int j = 0; j < FN; j++)
                    acc[i][j] = __builtin_amdgcn_mfma_f32_16x16x32_bf16(af[kh][i], bg[kh][j], acc[i][j], 0, 0, 0);
        __syncthreads();
    }

    // epilogue: C/D layout col=lane&15, row=quad*4+r (verified m89/m91)
#pragma unroll
    for (int i = 0; i < FM; i++) {
        int gm0 = m0 + wr * (TM / 2) + i * 16 + quad * 4;
#pragma unroll
        for (int j = 0; j < FN; j++) {
            int gn = n0 + wc * (TN / 2) + j * 16 + l16;
            if (gn >= N) continue;
            float bn = (biasMode == 1) ? bias[gn] : 0.0f;
#pragma unroll
            for (int r = 0; r < 4; r++) {
                int gm = gm0 + r;
                if (gm >= M) continue;
                float v = acc[i][j][r] * alpha + bn;
                if (biasMode == 2) v += bias[gm];
                long idx = (long)bz * sC + (long)gm * ldc + gn;
                if (OUT_BF16) ((u16*)Cm)[idx] = f2bf(v);
                else ((float*)Cm)[idx] = v;
            }
        }
    }
}

// ---------------- fused attention: scores+softmax+PV for one (head, 32-q-row) block ---
__global__ __launch_bounds__(128) void k_attn(
    const u16* __restrict__ qkv, const u16* __restrict__ vT, u16* __restrict__ Ob)
{
    __shared__ u16 Ks[2][4096];   // plane layout: idx(key,d) = (d>>5)*2048 + key*32 + (d&31)
    __shared__ u16 Vs[2][4096];   // idx(d,key)   = (key>>5)*2048 + d*32 + (key&31)
    __shared__ u16 Pl[32 * 72];   // [q_local][72]; 144B rows -> 16B-aligned
    int qb = blockIdx.x, h = blockIdx.y;
    int tid = threadIdx.x;
    int w = tid >> 6, lane = tid & 63;
    int quad = lane >> 4, l16 = lane & 15;

    int qrow = qb * 32 + w * 16 + l16;
    bf16x8 aq[2];
#pragma unroll
    for (int c = 0; c < 2; c++)
        aq[c] = *(const bf16x8*)&qkv[(long)qrow * 3072 + h * 64 + c * 32 + quad * 8];

    f32x4 acc_o[4];
#pragma unroll
    for (int j = 0; j < 4; j++) acc_o[j] = {0.f, 0.f, 0.f, 0.f};
    float mrow[4], lrow[4];
#pragma unroll
    for (int r = 0; r < 4; r++) { mrow[r] = -1e30f; lrow[r] = 0.f; }

    {
        int kt = 0;
#pragma unroll
        for (int rr = 0; rr < 4; rr++) {
            int c = rr * 2 + w;
            int loc = (c & 3) * 16 + (lane >> 2);
            int off8 = ((c >> 2) << 5) + (lane & 3) * 8;
            ASYNC_CP16(&qkv[(long)(kt * 64 + loc) * 3072 + 1024 + h * 64 + off8], &Ks[0][c * 512]);
            ASYNC_CP16(&vT[(long)(h * 64 + loc) * 512 + kt * 64 + off8], &Vs[0][c * 512]);
        }
    }
    __syncthreads();

    for (int kt = 0; kt < 8; kt++) {
        int buf = kt & 1;
        if (kt < 7) {
            int nb = buf ^ 1, ktn = kt + 1;
#pragma unroll
            for (int rr = 0; rr < 4; rr++) {
                int c = rr * 2 + w;
                int loc = (c & 3) * 16 + (lane >> 2);
                int off8 = ((c >> 2) << 5) + (lane & 3) * 8;
                ASYNC_CP16(&qkv[(long)(ktn * 64 + loc) * 3072 + 1024 + h * 64 + off8], &Ks[nb][c * 512]);
                ASYNC_CP16(&vT[(long)(h * 64 + loc) * 512 + ktn * 64 + off8], &Vs[nb][c * 512]);
            }
        }
        f32x4 s[4];
#pragma unroll
        for (int ss = 0; ss < 4; ss++) {
            s[ss] = {0.f, 0.f, 0.f, 0.f};
#pragma unroll
            for (int c = 0; c < 2; c++) {
                bf16x8 bk = *(const bf16x8*)&Ks[buf][c * 2048 + (ss * 16 + l16) * 32 + quad * 8];
                s[ss] = __builtin_amdgcn_mfma_f32_16x16x32_bf16(aq[c], bk, s[ss], 0, 0, 0);
            }
        }
        float mt[4];
#pragma unroll
        for (int r = 0; r < 4; r++) {
#pragma unroll
            for (int ss = 0; ss < 4; ss++) s[ss][r] *= 0.125f;
            mt[r] = fmaxf(fmaxf(s[0][r], s[1][r]), fmaxf(s[2][r], s[3][r]));
        }
#pragma unroll
        for (int mask = 1; mask < 16; mask <<= 1)
#pragma unroll
            for (int r = 0; r < 4; r++) mt[r] = fmaxf(mt[r], __shfl_xor(mt[r], mask));
        float al[4], rsum[4];
#pragma unroll
        for (int r = 0; r < 4; r++) {
            float mn = fmaxf(mrow[r], mt[r]);
            al[r] = exp2f((mrow[r] - mn) * L2E);
            mrow[r] = mn;
            rsum[r] = 0.f;
#pragma unroll
            for (int ss = 0; ss < 4; ss++) {
                float p = exp2f((s[ss][r] - mn) * L2E);
                s[ss][r] = p;
                rsum[r] += p;
            }
        }
#pragma unroll
        for (int mask = 1; mask < 16; mask <<= 1)
#pragma unroll
            for (int r = 0; r < 4; r++) rsum[r] += __shfl_xor(rsum[r], mask);
#pragma unroll
        for (int r = 0; r < 4; r++) lrow[r] = lrow[r] * al[r] + rsum[r];
#pragma unroll
        for (int j = 0; j < 4; j++)
#pragma unroll
            for (int r = 0; r < 4; r++) acc_o[j][r] *= al[r];
#pragma unroll
        for (int ss = 0; ss < 4; ss++)
#pragma unroll
            for (int r = 0; r < 4; r++)
                Pl[(w * 16 + quad * 4 + r) * 72 + ss * 16 + l16] = f2bf(s[ss][r]);
#pragma unroll
        for (int kc = 0; kc < 2; kc++) {
            bf16x8 ap = *(const bf16x8*)&Pl[(w * 16 + l16) * 72 + kc * 32 + quad * 8];
#pragma unroll
            for (int j = 0; j < 4; j++) {
                bf16x8 bv = *(const bf16x8*)&Vs[buf][kc * 2048 + (j * 16 + l16) * 32 + quad * 8];
                acc_o[j] = __builtin_amdgcn_mfma_f32_16x16x32_bf16(ap, bv, acc_o[j], 0, 0, 0);
            }
        }
        __syncthreads();
    }

#pragma unroll
    for (int r = 0; r < 4; r++) {
        float inv = 1.0f / lrow[r];
        int gq = qb * 32 + w * 16 + quad * 4 + r;
#pragma unroll
        for (int j = 0; j < 4; j++)
            Ob[(long)gq * 1024 + h * 64 + j * 16 + l16] = f2bf(acc_o[j][r] * inv);
    }
}

// ---------------- xb = bf16(LN(xb + s) * g + beta), in place, fp32 math ----------------
__global__ __launch_bounds__(256) void k_add_ln(
    u16* __restrict__ xb, const u16* __restrict__ s, int sBroadcast,
    const float* __restrict__ g, const float* __restrict__ beta)
{
    int row = blockIdx.x;             // b*512 + l
    int srow = sBroadcast ? (row & 511) : row;
    int tid = threadIdx.x;
    int d0 = tid * 4;
    u16* x = xb + (long)row * 1024;
    const u16* sp = s + (long)srow * 1024;
    ushort4 xv = *(const ushort4*)&x[d0];
    ushort4 sv = *(const ushort4*)&sp[d0];
    float v[4];
    v[0] = bf2f(xv.x) + bf2f(sv.x);
    v[1] = bf2f(xv.y) + bf2f(sv.y);
    v[2] = bf2f(xv.z) + bf2f(sv.z);
    v[3] = bf2f(xv.w) + bf2f(sv.w);
    float sum = v[0] + v[1] + v[2] + v[3];
    float sq = v[0] * v[0] + v[1] * v[1] + v[2] * v[2] + v[3] * v[3];
    for (int off = 32; off; off >>= 1) {
        sum += __shfl_down(sum, off);
        sq += __shfl_down(sq, off);
    }
    __shared__ float rs[4], rq[4];
    if ((tid & 63) == 0) { rs[tid >> 6] = sum; rq[tid >> 6] = sq; }
    __syncthreads();
    sum = rs[0] + rs[1] + rs[2] + rs[3];
    sq  = rq[0] + rq[1] + rq[2] + rq[3];
    float mean = sum * (1.f / 1024.f);
    float var = sq * (1.f / 1024.f) - mean * mean;
    float rstd = rsqrtf(var + LN_EPS);
    float4 gv = *(const float4*)&g[d0];
    float4 bv = *(const float4*)&beta[d0];
    ushort4 o;
    o.x = f2bf((v[0] - mean) * rstd * gv.x + bv.x);
    o.y = f2bf((v[1] - mean) * rstd * gv.y + bv.y);
    o.z = f2bf((v[2] - mean) * rstd * gv.z + bv.z);
    o.w = f2bf((v[3] - mean) * rstd * gv.w + bv.w);
    *(ushort4*)&x[d0] = o;
}

// ---------------- fused pool+head: out[b][c] = (mean_l x[b][l])·wf[:,c] + bf[c] -----
__global__ __launch_bounds__(256) void k_pool_head(
    const u16* __restrict__ xb, const float* __restrict__ wf,
    const float* __restrict__ bfin, float* __restrict__ out)
{
    int b = blockIdx.x;
    int tid = threadIdx.x;
    __shared__ float pl[1024];
    int d0 = tid * 4;
    const u16* x = xb + (long)b * 512 * 1024;
    float s0 = 0.f, s1 = 0.f, s2 = 0.f, s3 = 0.f;
    for (int l = 0; l < 512; l++) {
        ushort4 v = *(const ushort4*)&x[(long)l * 1024 + d0];
        s0 += bf2f(v.x); s1 += bf2f(v.y); s2 += bf2f(v.z); s3 += bf2f(v.w);
    }
    pl[d0] = s0 * (1.f / 512.f);
    pl[d0 + 1] = s1 * (1.f / 512.f);
    pl[d0 + 2] = s2 * (1.f / 512.f);
    pl[d0 + 3] = s3 * (1.f / 512.f);
    __syncthreads();
    __shared__ float red[4];
    for (int c = 0; c < 10; c++) {
        float t = 0.f;
        for (int d = tid; d < 1024; d += 256) t += pl[d] * wf[(long)d * 10 + c];
        for (int off = 32; off; off >>= 1) t += __shfl_down(t, off);
        if ((tid & 63) == 0) red[tid >> 6] = t;
        __syncthreads();
        if (tid == 0) out[b * 10 + c] = red[0] + red[1] + red[2] + red[3] + bfin[c];
        __syncthreads();
    }
}

// ---------------- host side ----------------
template <int TM, int TN>
static void gemm(bool outBf16, const u16* A, long lda, long sA,
                 const u16* B, long ldb, long sB,
                 void* C, long ldc, long sC,
                 int M, int N, int K, const float* bias, int biasMode, float alpha,
                 int batch, hipStream_t st)
{
    dim3 g((N + TN - 1) / TN, (M + TM - 1) / TM, batch);
    if (outBf16)
        k_gemm_nt<TM, TN, true><<<g, 256, 0, st>>>(A, lda, sA, B, ldb, sB, C, ldc, sC, M, N, K, bias, biasMode, alpha);
    else
        k_gemm_nt<TM, TN, false><<<g, 256, 0, st>>>(A, lda, sA, B, ldb, sB, C, ldc, sC, M, N, K, bias, biasMode, alpha);
}

extern "C" void kernel_launch(void* const* d_in, const int* in_sizes, int n_in,
                              void* d_out, int out_size, void* d_ws, size_t ws_size,
                              hipStream_t stream)
{
    const int* ids   = (const int*)d_in[0];
    const float* emb = (const float*)d_in[1];
    const float* pe  = (const float*)d_in[2];
    const float* wq  = (const float*)d_in[3];
    const float* bq  = (const float*)d_in[4];
    const float* wk  = (const float*)d_in[5];
    const float* bk  = (const float*)d_in[6];
    const float* wv  = (const float*)d_in[7];
    const float* bv  = (const float*)d_in[8];
    const float* wo  = (const float*)d_in[9];
    const float* bo  = (const float*)d_in[10];
    const float* w1  = (const float*)d_in[11];
    const float* b1  = (const float*)d_in[12];
    const float* w2  = (const float*)d_in[13];
    const float* b2  = (const float*)d_in[14];
    const float* g1  = (const float*)d_in[15];
    const float* be1 = (const float*)d_in[16];
    const float* g2  = (const float*)d_in[17];
    const float* be2 = (const float*)d_in[18];
    const float* wf  = (const float*)d_in[19];
    const float* bfi = (const float*)d_in[20];
    float* out = (float*)d_out;

    char* base = (char*)d_ws;
    size_t off = 0;
    auto alloc = [&](size_t bytes) {
        char* p = base + off;
        off = (off + bytes + 255) & ~(size_t)255;
        return p;
    };
    u16*   xb    = (u16*)  alloc(16UL * 512 * 1024 * 2);   // bf16 residual stream [B,L,D]
    u16*   wqkvT = (u16*)  alloc(3072UL * 1024 * 2);       // [3072,1024] = wqT;wkT;wvT
    u16*   woT   = (u16*)  alloc(1024UL * 1024 * 2);
    u16*   w1T   = (u16*)  alloc(4096UL * 1024 * 2);       // [F,D]
    u16*   w2T   = (u16*)  alloc(1024UL * 4096 * 2);       // [D,F]
    float* qkvb  = (float*)alloc(3072UL * 4);              // concat(bq,bk,bv)
    u16*   qkv   = (u16*)  alloc(512UL * 3072 * 2);        // [L, 3*D] = q|k|v
    u16*   vT    = (u16*)  alloc(1024UL * 512 * 2);        // v transposed [D,L]
    u16*   Ob    = (u16*)  alloc(512UL * 1024 * 2);        // attn context bf16 [L,D]
    u16*   src2  = (u16*)  alloc(512UL * 1024 * 2);        // bf16
    u16*   Hb    = (u16*)  alloc(8192UL * 4096 * 2);       // FFN hidden bf16
    u16*   ffb   = (u16*)  alloc(8192UL * 1024 * 2);       // bf16

    // weight conversion (every launch: ws re-poisoned)
    k_transpose_bf16<<<dim3(32, 32), 256, 0, stream>>>(wq, wqkvT + 0,             1024, 1024, 1024);
    k_transpose_bf16<<<dim3(32, 32), 256, 0, stream>>>(wk, wqkvT + 1024UL * 1024, 1024, 1024, 1024);
    k_transpose_bf16<<<dim3(32, 32), 256, 0, stream>>>(wv, wqkvT + 2048UL * 1024, 1024, 1024, 1024);
    k_transpose_bf16<<<dim3(32, 32), 256, 0, stream>>>(wo, woT, 1024, 1024, 1024);
    k_transpose_bf16<<<dim3(128, 32), 256, 0, stream>>>(w1, w1T, 1024, 4096, 1024);
    k_transpose_bf16<<<dim3(32, 128), 256, 0, stream>>>(w2, w2T, 4096, 1024, 4096);
    k_concat3<<<12, 256, 0, stream>>>(bq, bk, bv, qkvb);

    k_embed<<<8192, 256, 0, stream>>>(ids, emb, pe, xb);

    for (int layer = 0; layer < 6; layer++) {
        // fused q|k|v for batch 0: [512,3072] = xb[0:512] @ wqkvT^T + qkvb (64-tile: 384 blocks)
        gemm<64, 64>(true, xb, 1024, 0, wqkvT, 1024, 0, qkv, 3072, 0, 512, 3072, 1024, qkvb, 1, 1.f, 1, stream);
        // vT[d][l] from v part of qkv
        k_transpose_bb<<<dim3(32, 16), 256, 0, stream>>>(qkv + 2048, 3072, vT, 512);
        // fused scores+softmax+PV
        k_attn<<<dim3(16, 16), 128, 0, stream>>>(qkv, vT, Ob);
        // src2 = O . wo + bo (64-tile: 128 blocks)
        gemm<64, 64>(true, Ob, 1024, 0, woT, 1024, 0, src2, 1024, 0, 512, 1024, 1024, bo, 1, 1.f, 1, stream);
        k_add_ln<<<8192, 256, 0, stream>>>(xb, src2, 1, g1, be1);
        // FFN (128-tiles)
        gemm<128, 128>(true, xb, 1024, 0, w1T, 1024, 0, Hb, 4096, 0, 8192, 4096, 1024, b1, 1, 1.f, 1, stream);
        gemm<128, 128>(true, Hb, 4096, 0, w2T, 4096, 0, ffb, 1024, 0, 8192, 1024, 4096, b2, 1, 1.f, 1, stream);
        k_add_ln<<<8192, 256, 0, stream>>>(xb, ffb, 0, g2, be2);
    }

    k_pool_head<<<16, 256, 0, stream>>>(xb, wf, bfi, out);
}